// Round 10
// baseline (352.343 us; speedup 1.0000x reference)
//
#include <hip/hip_runtime.h>
#include <hip/hip_bf16.h>
#include <cfloat>

// VecPointNet on MI355X, round 10:
//  - GEMM: 512 blocks (2/CU -> 4 waves/SIMD), 8 waves each owning ONE P-frag +
//    ONE D-frag (24 acc VGPRs), __launch_bounds__(512,4) caps VGPR at 128,
//    ks-loop unroll limited to 2 to keep in-flight loads under the cap.
//    (r5 failed this with the 2-frag body: ~150 regs under a 128 cap -> spills.)
//  - kNN: x2 chunk unroll on stale-T inserts (T refresh once per 128 cands).
//  - Rest identical to r9 (321us).

typedef __attribute__((ext_vector_type(8))) short short8;
typedef __attribute__((ext_vector_type(4))) float f32x4;

__device__ __forceinline__ unsigned short f2bf(float f) {
    union { float f; unsigned u; } v; v.f = f;
    unsigned r = v.u + 0x7fffu + ((v.u >> 16) & 1u);
    return (unsigned short)(r >> 16);
}
__device__ __forceinline__ float bf2f(unsigned short h) {
    union { unsigned u; float f; } v; v.u = ((unsigned)h) << 16;
    return v.f;
}

// ---------------- setup: prep (pts4) + weight pack ----------------
__global__ __launch_bounds__(256) void setup_kernel(const float* __restrict__ x,
                                                    float4* __restrict__ pts4,
                                                    const float* __restrict__ Wl,
                                                    const float* __restrict__ Ul,
                                                    const float* __restrict__ Wg,
                                                    const float* __restrict__ Ug,
                                                    const float* __restrict__ Wout,
                                                    unsigned short* __restrict__ Ah,
                                                    unsigned short* __restrict__ Al,
                                                    int N, int B) {
    int t = blockIdx.x * 256 + threadIdx.x;     // 0..327679
    if (t < B * N) {
        int b = t / N, n = t - b * N;
        const float* xb = x + (long)b * 3 * N;
        float px = xb[n], py = xb[N + n], pz = xb[2 * N + n];
        pts4[t] = make_float4(px, py, pz, px * px + py * py + pz * pz);
    }
    int g, r, M; long base;
    if (t < 262144) { g = t >> 15; r = t & 32767; M = 256; base = (long)g << 15; }
    else { int t2 = t - 262144; g = 8 + (t2 >> 14); r = t2 & 16383; M = 128;
           base = 262144 + (long)(g - 8) * 16384; }
    int MF = M >> 4;
    int ks = r / (MF * 512);
    int mf = (r >> 9) % MF;
    int lane = (r >> 3) & 63;
    int j = r & 7;
    int m = mf * 16 + (lane & 15);
    int k = ks * 32 + ((lane >> 4) << 3) + j;
    const float* src; int ldw; int row;
    if (g < 4) {
        ldw = 128; row = m & 127;
        src = (m < 128) ? (Wl + (long)g * 128 * 128) : (Ul + (long)g * 128 * 128);
    } else if (g < 8) {
        ldw = 256; row = m & 127;
        int l = g - 4;
        src = (m < 128) ? (Wg + (long)l * 128 * 256) : (Ug + (long)l * 128 * 256);
    } else {
        ldw = 512; row = m;
        src = Wout + (g - 8) * 128;
    }
    float v = src[(long)row * ldw + k];
    unsigned short h = f2bf(v);
    Ah[base + r] = h;
    Al[base + r] = f2bf(v - bf2f(h));
}

// ---------------- knn: wave/query, stale-T batched inserts, x2 unroll ----------------
__global__ __launch_bounds__(1024) void knn_kernel(const float4* __restrict__ pts4,
                                                   int* __restrict__ idxOut, int N) {
    __shared__ float4 cbuf[4096];   // 64 KB
    int t = threadIdx.x;
    int tilesPerB = N / 16;
    int b = blockIdx.x / tilesPerB;
    int q = (blockIdx.x % tilesPerB) * 16 + (t >> 6);
    int lane = t & 63;

    for (int i = t; i < N; i += 1024) cbuf[i] = pts4[b * N + i];
    __syncthreads();

    float4 Q = cbuf[q];
    unsigned ku = 0xFFFFFFFFu; int ki = 0x7fffffff;   // lanes 0..15: sorted list
    unsigned Tu = 0xFFFFFFFFu; int Ti = 0x7fffffff;   // stale 16th-best

#define KNN_INS(MASK, UU, CI)                                             \
    while (MASK) {                                                        \
        int src = __ffsll(MASK) - 1;                                      \
        MASK &= MASK - 1;                                                 \
        unsigned vu = (unsigned)__shfl((int)(UU), src);                   \
        int      vi = __shfl((CI), src);                                  \
        unsigned kum1 = (unsigned)__shfl_up((int)ku, 1);                  \
        int      kim1 = __shfl_up(ki, 1);                                 \
        if (lane == 0) { kum1 = 0u; kim1 = (-2147483647 - 1); }           \
        bool lem1 = (vu < kum1) || (vu == kum1 && vi < kim1);             \
        bool ltj  = (vu < ku)   || (vu == ku   && vi < ki);               \
        unsigned knu = lem1 ? kum1 : (ltj ? vu : ku);                     \
        int      kni = lem1 ? kim1 : (ltj ? vi : ki);                     \
        if (lane < 16) { ku = knu; ki = kni; }                            \
    }

    for (int c0 = 0; c0 < N; c0 += 128) {
        float4 Ca = cbuf[c0 + lane];
        float4 Cb = cbuf[c0 + 64 + lane];
        float dota = Q.x * Ca.x + Q.y * Ca.y + Q.z * Ca.z;
        float dotb = Q.x * Cb.x + Q.y * Cb.y + Q.z * Cb.z;
        float d2a = Q.w + Ca.w - 2.0f * dota;         // same formula as reference
        float d2b = Q.w + Cb.w - 2.0f * dotb;
        unsigned ua = __float_as_uint(d2a);
        unsigned ub = __float_as_uint(d2b);
        ua ^= (unsigned)((int)ua >> 31) | 0x80000000u;
        ub ^= (unsigned)((int)ub >> 31) | 0x80000000u;
        int cia = c0 + lane, cib = c0 + 64 + lane;
        bool qa = (ua < Tu) || (ua == Tu && cia < Ti);
        bool qb = (ub < Tu) || (ub == Tu && cib < Ti);
        unsigned long long ma = __ballot(qa);
        unsigned long long mb = __ballot(qb);
        KNN_INS(ma, ua, cia);
        KNN_INS(mb, ub, cib);
        Tu = (unsigned)__shfl((int)ku, 15);
        Ti = __shfl(ki, 15);
    }
#undef KNN_INS
    if (lane < 16) idxOut[(b * N + q) * 16 + lane] = ki;
}

// ---------------- edge features + input LNA + mean over K -> f0 bf16 hi/lo ----------------
__global__ __launch_bounds__(256) void edge_kernel(const float4* __restrict__ pts4,
                                                   const int* __restrict__ idx,
                                                   const float* __restrict__ Win,
                                                   const float* __restrict__ Uin,
                                                   unsigned short* __restrict__ Yh,
                                                   unsigned short* __restrict__ Yl,
                                                   int N) {
    __shared__ float4 nbuf[8][16];
    __shared__ float4 cpt[8];
    int nTiles = N / 8;
    int b = blockIdx.x / nTiles;
    int n0 = (blockIdx.x % nTiles) * 8;
    int t = threadIdx.x;
    if (t < 128) {
        int pl = t >> 4, k = t & 15;
        int nb = idx[(b * N + n0 + pl) * 16 + k];
        nbuf[pl][k] = pts4[b * N + nb];
    } else if (t < 136) {
        cpt[t - 128] = pts4[b * N + n0 + (t - 128)];
    }
    __syncthreads();
    int o = t & 127, h = t >> 7;
    float w0 = Win[o * 3], w1 = Win[o * 3 + 1], w2 = Win[o * 3 + 2];
    float u0 = Uin[o * 3], u1 = Uin[o * 3 + 1], u2 = Uin[o * 3 + 2];
    for (int pl = h * 4; pl < h * 4 + 4; ++pl) {
        float4 c4 = cpt[pl];
        float inv = 1.0f / fmaxf(sqrtf(c4.w), 1e-12f);
        float ax = c4.x * inv, ay = c4.y * inv, az = c4.z * inv;
        float a0 = 0.f, a1 = 0.f, a2 = 0.f;
        for (int k = 0; k < 16; ++k) {
            float4 nb = nbuf[pl][k];
            float cr0 = ay * nb.z - az * nb.y;
            float cr1 = az * nb.x - ax * nb.z;
            float cr2 = ax * nb.y - ay * nb.x;
            float df0 = nb.x - c4.x, df1 = nb.y - c4.y, df2 = nb.z - c4.z;
            float P0 = w0 * cr0 + w1 * df0 + w2 * c4.x;
            float P1 = w0 * cr1 + w1 * df1 + w2 * c4.y;
            float P2 = w0 * cr2 + w1 * df2 + w2 * c4.z;
            float D0 = u0 * cr0 + u1 * df0 + u2 * c4.x;
            float D1 = u0 * cr1 + u1 * df1 + u2 * c4.y;
            float D2 = u0 * cr2 + u1 * df2 + u2 * c4.z;
            float dot = P0 * D0 + P1 * D1 + P2 * D2;
            float dsq = D0 * D0 + D1 * D1 + D2 * D2;
            if (dot < 0.0f) {
                float s = dot / (dsq + 1e-6f);
                P0 -= s * D0; P1 -= s * D1; P2 -= s * D2;
            }
            a0 += P0; a1 += P1; a2 += P2;
        }
        float vals[3] = { a0 * (1.0f / 16.0f), a1 * (1.0f / 16.0f), a2 * (1.0f / 16.0f) };
        long n = n0 + pl;
#pragma unroll
        for (int c = 0; c < 3; ++c) {
            long off = ((long)(b * 3 + c) * 4096 + n) * 128 + o;
            unsigned short hh = f2bf(vals[c]);
            Yh[off] = hh;
            Yl[off] = f2bf(vals[c] - bf2f(hh));
        }
    }
}

// ---------------- MFMA GEMM, bf16x3, one-frag-per-wave, 512 blocks ----------------
// MODE 0: LNA; emits per-tile yg partials. MODE 1: LNA + bias + fused Wout.
// Grid: 512 blocks (b*256 + tile16), 512 threads; wave w owns P-frag mf=w and
// D-frag mf=8+w. launch_bounds(512,4): VGPR<=128 -> 2 blocks/CU = 4 waves/SIMD.
template<int MODE>
__global__ __launch_bounds__(512, 4) void gemm_kernel(
    const unsigned short* __restrict__ Aph, const unsigned short* __restrict__ Apl,
    long aOff, long aOffOut,
    const unsigned short* __restrict__ Bh, const unsigned short* __restrict__ Bl,
    const float* __restrict__ biasP, const float* __restrict__ biasD,
    unsigned short* __restrict__ Oh, unsigned short* __restrict__ Ol,
    float* __restrict__ Ofp, float* __restrict__ part, int accum)
{
    const int N = 4096;
    __shared__ unsigned short ylds[MODE == 1 ? 3 : 1][2][2048];   // 24 KB (MODE1)
    int t = threadIdx.x;
    int lane = t & 63, w = t >> 6;
    int b = blockIdx.x >> 8;
    int tile = blockIdx.x & 255;
    int ncol = tile * 16 + (lane & 15);
    int kq = (lane >> 4) << 3;

    f32x4 accP[3] = {};
    f32x4 accD[3] = {};

    const unsigned short* AhB = Aph + aOff;
    const unsigned short* AlB = Apl + aOff;

#pragma unroll 2
    for (int ks = 0; ks < 4; ++ks) {
        short8 bh[3], bl[3];
#pragma unroll
        for (int c = 0; c < 3; ++c) {
            long boff = ((long)(b * 3 + c) * N + ncol) * 128 + ks * 32 + kq;
            bh[c] = *(const short8*)(Bh + boff);
            bl[c] = *(const short8*)(Bl + boff);
        }
        long aoffP = (((long)ks * 16 + w) * 64 + lane) * 8;
        short8 ahP = *(const short8*)(AhB + aoffP);
        short8 alP = *(const short8*)(AlB + aoffP);
#pragma unroll
        for (int c = 0; c < 3; ++c) {
            accP[c] = __builtin_amdgcn_mfma_f32_16x16x32_bf16(ahP, bh[c], accP[c], 0, 0, 0);
            accP[c] = __builtin_amdgcn_mfma_f32_16x16x32_bf16(ahP, bl[c], accP[c], 0, 0, 0);
            accP[c] = __builtin_amdgcn_mfma_f32_16x16x32_bf16(alP, bh[c], accP[c], 0, 0, 0);
        }
        long aoffD = (((long)ks * 16 + 8 + w) * 64 + lane) * 8;
        short8 ahD = *(const short8*)(AhB + aoffD);
        short8 alD = *(const short8*)(AlB + aoffD);
#pragma unroll
        for (int c = 0; c < 3; ++c) {
            accD[c] = __builtin_amdgcn_mfma_f32_16x16x32_bf16(ahD, bh[c], accD[c], 0, 0, 0);
            accD[c] = __builtin_amdgcn_mfma_f32_16x16x32_bf16(ahD, bl[c], accD[c], 0, 0, 0);
            accD[c] = __builtin_amdgcn_mfma_f32_16x16x32_bf16(alD, bh[c], accD[c], 0, 0, 0);
        }
    }

    int obase = 16 * w + ((lane >> 4) << 2);
    float Pv[3][4];
#pragma unroll
    for (int r = 0; r < 4; ++r) {
        int o = obase + r;
        float P[3], D[3];
#pragma unroll
        for (int c = 0; c < 3; ++c) {
            P[c] = accP[c][r];
            D[c] = accD[c][r];
            if (MODE == 1) {
                long bb = ((long)(b * 128 + o)) * 3 + c;
                P[c] += biasP[bb];
                D[c] += biasD[bb];
            }
        }
        float dot = P[0] * D[0] + P[1] * D[1] + P[2] * D[2];
        float dsq = D[0] * D[0] + D[1] * D[1] + D[2] * D[2];
        if (dot < 0.0f) {
            float s = dot / (dsq + 1e-6f);
            P[0] -= s * D[0]; P[1] -= s * D[1]; P[2] -= s * D[2];
        }
        Pv[0][r] = P[0]; Pv[1][r] = P[1]; Pv[2][r] = P[2];
    }

#pragma unroll
    for (int c = 0; c < 3; ++c) {
        unsigned short hs[4], ls[4];
#pragma unroll
        for (int r = 0; r < 4; ++r) {
            hs[r] = f2bf(Pv[c][r]);
            ls[r] = f2bf(Pv[c][r] - bf2f(hs[r]));
        }
        long ooff = ((long)(b * 3 + c) * N + ncol) * 128 + obase;
        *(ushort4*)(Oh + ooff) = make_ushort4(hs[0], hs[1], hs[2], hs[3]);
        *(ushort4*)(Ol + ooff) = make_ushort4(ls[0], ls[1], ls[2], ls[3]);
        if (MODE == 1) {
            int li = ((obase >> 3) << 7) + ((lane & 15) << 3) + (obase & 7);
            *(ushort4*)&ylds[c][0][li] = make_ushort4(hs[0], hs[1], hs[2], hs[3]);
            *(ushort4*)&ylds[c][1][li] = make_ushort4(ls[0], ls[1], ls[2], ls[3]);
        }
    }

    if (MODE == 0) {
        // yg partials over this block's 16 cols; segment = tile.
#pragma unroll
        for (int c = 0; c < 3; ++c) {
#pragma unroll
            for (int r = 0; r < 4; ++r) {
                float v = Pv[c][r];
                v += __shfl_xor(v, 1);
                v += __shfl_xor(v, 2);
                v += __shfl_xor(v, 4);
                v += __shfl_xor(v, 8);
                if ((lane & 15) == 0)
                    part[((long)(b * 3 + c) * 256 + tile) * 128 + (obase + r)] = v;
            }
        }
    }

    if (MODE == 1) {
        __syncthreads();
        f32x4 accO[3] = {};
        const unsigned short* AoH = Aph + aOffOut;
        const unsigned short* AoL = Apl + aOffOut;
#pragma unroll
        for (int ks = 0; ks < 4; ++ks) {
            short8 yh[3], yl[3];
            int li = (((ks << 2) + (lane >> 4)) << 7) + ((lane & 15) << 3);
#pragma unroll
            for (int c = 0; c < 3; ++c) {
                yh[c] = *(const short8*)&ylds[c][0][li];
                yl[c] = *(const short8*)&ylds[c][1][li];
            }
            long aoff = (((long)ks * 8 + w) * 64 + lane) * 8;
            short8 ah = *(const short8*)(AoH + aoff);
            short8 al = *(const short8*)(AoL + aoff);
#pragma unroll
            for (int c = 0; c < 3; ++c) {
                accO[c] = __builtin_amdgcn_mfma_f32_16x16x32_bf16(ah, yh[c], accO[c], 0, 0, 0);
                accO[c] = __builtin_amdgcn_mfma_f32_16x16x32_bf16(ah, yl[c], accO[c], 0, 0, 0);
                accO[c] = __builtin_amdgcn_mfma_f32_16x16x32_bf16(al, yh[c], accO[c], 0, 0, 0);
            }
        }
#pragma unroll
        for (int r = 0; r < 4; ++r) {
            int o = obase + r;
#pragma unroll
            for (int c = 0; c < 3; ++c) {
                long off = ((long)(b * 128 + o) * 3 + c) * N + ncol;
                float v = accO[c][r];
                if (accum) v += Ofp[off];
                Ofp[off] = v;
            }
        }
    }
}

// ---------------- fused yg reduce + bias: 6 blocks (b*3+c), 1024 threads ----------------
__global__ __launch_bounds__(1024) void ygredbias_kernel(const float* __restrict__ part,
                                                         const float* __restrict__ Wg,
                                                         const float* __restrict__ Ug,
                                                         float* __restrict__ biasP,
                                                         float* __restrict__ biasD) {
    __shared__ float red[8][128];
    __shared__ float ygs[128];
    int bc = blockIdx.x;
    int t = threadIdx.x;
    int o = t & 127, g = t >> 7;
    float s = 0.f;
    for (int seg = g * 32; seg < g * 32 + 32; ++seg)
        s += part[((long)bc * 256 + seg) * 128 + o];
    red[g][o] = s;
    __syncthreads();
    if (t < 128) {
        float r = 0.f;
#pragma unroll
        for (int k = 0; k < 8; ++k) r += red[k][t];
        ygs[t] = r * (1.0f / 4096.0f);
    }
    __syncthreads();
    if (t < 256) {
        int oo = t & 127; bool isD = t >= 128;
        const float* row = (isD ? Ug : Wg) + oo * 256 + 128;
        float s2 = 0.f;
        for (int i = 0; i < 128; ++i) s2 = fmaf(row[i], ygs[i], s2);
        int b = bc / 3, c = bc % 3;
        (isD ? biasD : biasP)[((long)(b * 128 + oo)) * 3 + c] = s2;
    }
}

// ---------------- mean over N per (b, o, c) row of fp32 out1 ----------------
__global__ __launch_bounds__(256) void reduce_mean_kernel(const float* __restrict__ src, long bs,
                                                          float* __restrict__ dst, int N) {
    __shared__ float red[256];
    int row = blockIdx.x;
    int b = row / 384; int rr = row % 384;
    const float* p = src + (long)b * bs + (long)rr * N;
    float s = 0.f;
    for (int i = threadIdx.x; i < N; i += 256) s += p[i];
    red[threadIdx.x] = s;
    __syncthreads();
    for (int st = 128; st > 0; st >>= 1) {
        if (threadIdx.x < st) red[threadIdx.x] += red[threadIdx.x + st];
        __syncthreads();
    }
    if (threadIdx.x == 0) dst[row] = red[0] / (float)N;
}

extern "C" void kernel_launch(void* const* d_in, const int* in_sizes, int n_in,
                              void* d_out, int out_size, void* d_ws, size_t ws_size,
                              hipStream_t stream) {
    const float* x    = (const float*)d_in[0];
    const float* Win  = (const float*)d_in[1];
    const float* Uin  = (const float*)d_in[2];
    const float* Wl   = (const float*)d_in[3];
    const float* Ul   = (const float*)d_in[4];
    const float* Wg   = (const float*)d_in[5];
    const float* Ug   = (const float*)d_in[6];
    const float* Wout = (const float*)d_in[7];

    const int B = 2, N = 4096, H = 128;
    float* out0 = (float*)d_out;                 // (B,128,3) mean
    float* out1 = out0 + (long)B * H * 3;        // (B,128,3,N) fp32

    float* ws = (float*)d_ws;
    long off = 0;
    float4* pts4 = (float4*)ws;                  off += (long)B * N * 4;
    int* idx = (int*)(ws + off);                 off += (long)B * N * 16;
    const long ACT = (long)B * 3 * N * H;        // ushort count
    unsigned short* f0h = (unsigned short*)(ws + off);  off += ACT / 2;
    unsigned short* f0l = (unsigned short*)(ws + off);  off += ACT / 2;
    unsigned short* y1h = (unsigned short*)(ws + off);  off += ACT / 2;
    unsigned short* y1l = (unsigned short*)(ws + off);  off += ACT / 2;
    unsigned short* Aph = (unsigned short*)(ws + off);  off += 327680 / 2;
    unsigned short* Apl = (unsigned short*)(ws + off);  off += 327680 / 2;
    float* part  = ws + off;                     off += 6L * 256 * 128;
    float* biasP = ws + off;                     off += B * H * 3;
    float* biasD = ws + off;                     off += B * H * 3;
    // ~27.6 MB of workspace

    long bs128 = (long)H * 3 * N;

    setup_kernel<<<1280, 256, 0, stream>>>(x, pts4, Wl, Ul, Wg, Ug, Wout, Aph, Apl, N, B);
    knn_kernel<<<B * (N / 16), 1024, 0, stream>>>(pts4, idx, N);
    edge_kernel<<<B * (N / 8), 256, 0, stream>>>(pts4, idx, Win, Uin, f0h, f0l, N);

    for (int l = 0; l < 4; ++l) {
        gemm_kernel<0><<<512, 512, 0, stream>>>(
            Aph, Apl, (long)l * 32768, 0, f0h, f0l, nullptr, nullptr,
            y1h, y1l, nullptr, part, 0);
        ygredbias_kernel<<<6, 1024, 0, stream>>>(part,
            Wg + (long)l * H * 256, Ug + (long)l * H * 256, biasP, biasD);
        gemm_kernel<1><<<512, 512, 0, stream>>>(
            Aph, Apl, (long)(4 + l) * 32768, 262144 + (long)l * 16384,
            y1h, y1l, biasP, biasD, f0h, f0l, out1, nullptr, l > 0 ? 1 : 0);
    }
    reduce_mean_kernel<<<B * H * 3, 256, 0, stream>>>(out1, bs128, out0, N);
}

// Round 11
// 284.594 us; speedup vs baseline: 1.2381x; 1.2381x over previous
//
#include <hip/hip_runtime.h>
#include <hip/hip_bf16.h>
#include <cfloat>

// VecPointNet on MI355X, round 11:
//  - Base = r9 (321us, best). r10's two changes both regressed and are reverted.
//  - NEW: layer chaining. The inter-layer dataflow is column-local, so the
//    MODE-1 kernel gains a 3rd phase: MFMA the NEXT layer's Wl/Ul against the
//    y2 already staged in LDS (fragment order) -> emits y1(l+1) + yg partials.
//    gemm0 of layers 1..3 disappears; y2/f0 never round-trips global memory
//    (~88 MB saved). Dispatches 16 -> 12.

typedef __attribute__((ext_vector_type(8))) short short8;
typedef __attribute__((ext_vector_type(4))) float f32x4;

__device__ __forceinline__ unsigned short f2bf(float f) {
    union { float f; unsigned u; } v; v.f = f;
    unsigned r = v.u + 0x7fffu + ((v.u >> 16) & 1u);
    return (unsigned short)(r >> 16);
}
__device__ __forceinline__ float bf2f(unsigned short h) {
    union { unsigned u; float f; } v; v.u = ((unsigned)h) << 16;
    return v.f;
}

// ---------------- setup: prep (pts4) + weight pack ----------------
__global__ __launch_bounds__(256) void setup_kernel(const float* __restrict__ x,
                                                    float4* __restrict__ pts4,
                                                    const float* __restrict__ Wl,
                                                    const float* __restrict__ Ul,
                                                    const float* __restrict__ Wg,
                                                    const float* __restrict__ Ug,
                                                    const float* __restrict__ Wout,
                                                    unsigned short* __restrict__ Ah,
                                                    unsigned short* __restrict__ Al,
                                                    int N, int B) {
    int t = blockIdx.x * 256 + threadIdx.x;     // 0..327679
    if (t < B * N) {
        int b = t / N, n = t - b * N;
        const float* xb = x + (long)b * 3 * N;
        float px = xb[n], py = xb[N + n], pz = xb[2 * N + n];
        pts4[t] = make_float4(px, py, pz, px * px + py * py + pz * pz);
    }
    int g, r, M; long base;
    if (t < 262144) { g = t >> 15; r = t & 32767; M = 256; base = (long)g << 15; }
    else { int t2 = t - 262144; g = 8 + (t2 >> 14); r = t2 & 16383; M = 128;
           base = 262144 + (long)(g - 8) * 16384; }
    int MF = M >> 4;
    int ks = r / (MF * 512);
    int mf = (r >> 9) % MF;
    int lane = (r >> 3) & 63;
    int j = r & 7;
    int m = mf * 16 + (lane & 15);
    int k = ks * 32 + ((lane >> 4) << 3) + j;
    const float* src; int ldw; int row;
    if (g < 4) {
        ldw = 128; row = m & 127;
        src = (m < 128) ? (Wl + (long)g * 128 * 128) : (Ul + (long)g * 128 * 128);
    } else if (g < 8) {
        ldw = 256; row = m & 127;
        int l = g - 4;
        src = (m < 128) ? (Wg + (long)l * 128 * 256) : (Ug + (long)l * 128 * 256);
    } else {
        ldw = 512; row = m;
        src = Wout + (g - 8) * 128;
    }
    float v = src[(long)row * ldw + k];
    unsigned short h = f2bf(v);
    Ah[base + r] = h;
    Al[base + r] = f2bf(v - bf2f(h));
}

// ---------------- knn (r9 exact): wave/query, stale-T batched inserts ----------------
__global__ __launch_bounds__(1024) void knn_kernel(const float4* __restrict__ pts4,
                                                   int* __restrict__ idxOut, int N) {
    __shared__ float4 cbuf[4096];   // 64 KB
    int t = threadIdx.x;
    int tilesPerB = N / 16;
    int b = blockIdx.x / tilesPerB;
    int q = (blockIdx.x % tilesPerB) * 16 + (t >> 6);
    int lane = t & 63;

    for (int i = t; i < N; i += 1024) cbuf[i] = pts4[b * N + i];
    __syncthreads();

    float4 Q = cbuf[q];
    unsigned ku = 0xFFFFFFFFu; int ki = 0x7fffffff;   // lanes 0..15: sorted list
    unsigned Tu = 0xFFFFFFFFu; int Ti = 0x7fffffff;   // stale 16th-best

    for (int c0 = 0; c0 < N; c0 += 64) {
        float4 C = cbuf[c0 + lane];
        float dot = Q.x * C.x + Q.y * C.y + Q.z * C.z;
        float d2 = Q.w + C.w - 2.0f * dot;            // same formula as reference
        unsigned u = __float_as_uint(d2);
        u ^= (unsigned)((int)u >> 31) | 0x80000000u;  // orderable uint
        int ci = c0 + lane;
        bool qual = (u < Tu) || (u == Tu && ci < Ti);
        unsigned long long mask = __ballot(qual);
        while (mask) {
            int src = __ffsll(mask) - 1;
            mask &= mask - 1;
            unsigned vu = (unsigned)__shfl((int)u, src);
            int      vi = __shfl(ci, src);
            unsigned kum1 = (unsigned)__shfl_up((int)ku, 1);
            int      kim1 = __shfl_up(ki, 1);
            if (lane == 0) { kum1 = 0u; kim1 = (-2147483647 - 1); }
            bool lem1 = (vu < kum1) || (vu == kum1 && vi < kim1);
            bool ltj  = (vu < ku)   || (vu == ku   && vi < ki);
            unsigned knu = lem1 ? kum1 : (ltj ? vu : ku);
            int      kni = lem1 ? kim1 : (ltj ? vi : ki);
            if (lane < 16) { ku = knu; ki = kni; }
        }
        Tu = (unsigned)__shfl((int)ku, 15);
        Ti = __shfl(ki, 15);
    }
    if (lane < 16) idxOut[(b * N + q) * 16 + lane] = ki;
}

// ---------------- edge features + input LNA + mean over K -> f0 bf16 hi/lo ----------------
__global__ __launch_bounds__(256) void edge_kernel(const float4* __restrict__ pts4,
                                                   const int* __restrict__ idx,
                                                   const float* __restrict__ Win,
                                                   const float* __restrict__ Uin,
                                                   unsigned short* __restrict__ Yh,
                                                   unsigned short* __restrict__ Yl,
                                                   int N) {
    __shared__ float4 nbuf[8][16];
    __shared__ float4 cpt[8];
    int nTiles = N / 8;
    int b = blockIdx.x / nTiles;
    int n0 = (blockIdx.x % nTiles) * 8;
    int t = threadIdx.x;
    if (t < 128) {
        int pl = t >> 4, k = t & 15;
        int nb = idx[(b * N + n0 + pl) * 16 + k];
        nbuf[pl][k] = pts4[b * N + nb];
    } else if (t < 136) {
        cpt[t - 128] = pts4[b * N + n0 + (t - 128)];
    }
    __syncthreads();
    int o = t & 127, h = t >> 7;
    float w0 = Win[o * 3], w1 = Win[o * 3 + 1], w2 = Win[o * 3 + 2];
    float u0 = Uin[o * 3], u1 = Uin[o * 3 + 1], u2 = Uin[o * 3 + 2];
    for (int pl = h * 4; pl < h * 4 + 4; ++pl) {
        float4 c4 = cpt[pl];
        float inv = 1.0f / fmaxf(sqrtf(c4.w), 1e-12f);
        float ax = c4.x * inv, ay = c4.y * inv, az = c4.z * inv;
        float a0 = 0.f, a1 = 0.f, a2 = 0.f;
        for (int k = 0; k < 16; ++k) {
            float4 nb = nbuf[pl][k];
            float cr0 = ay * nb.z - az * nb.y;
            float cr1 = az * nb.x - ax * nb.z;
            float cr2 = ax * nb.y - ay * nb.x;
            float df0 = nb.x - c4.x, df1 = nb.y - c4.y, df2 = nb.z - c4.z;
            float P0 = w0 * cr0 + w1 * df0 + w2 * c4.x;
            float P1 = w0 * cr1 + w1 * df1 + w2 * c4.y;
            float P2 = w0 * cr2 + w1 * df2 + w2 * c4.z;
            float D0 = u0 * cr0 + u1 * df0 + u2 * c4.x;
            float D1 = u0 * cr1 + u1 * df1 + u2 * c4.y;
            float D2 = u0 * cr2 + u1 * df2 + u2 * c4.z;
            float dot = P0 * D0 + P1 * D1 + P2 * D2;
            float dsq = D0 * D0 + D1 * D1 + D2 * D2;
            if (dot < 0.0f) {
                float s = dot / (dsq + 1e-6f);
                P0 -= s * D0; P1 -= s * D1; P2 -= s * D2;
            }
            a0 += P0; a1 += P1; a2 += P2;
        }
        float vals[3] = { a0 * (1.0f / 16.0f), a1 * (1.0f / 16.0f), a2 * (1.0f / 16.0f) };
        long n = n0 + pl;
#pragma unroll
        for (int c = 0; c < 3; ++c) {
            long off = ((long)(b * 3 + c) * 4096 + n) * 128 + o;
            unsigned short hh = f2bf(vals[c]);
            Yh[off] = hh;
            Yl[off] = f2bf(vals[c] - bf2f(hh));
        }
    }
}

// ---------------- gemm0: y1 = LNA(Wl0 f0, Ul0 f0) + yg partials (r9 MODE 0) ----------------
__global__ __launch_bounds__(512, 1) void gemm0_kernel(
    const unsigned short* __restrict__ Aph, const unsigned short* __restrict__ Apl,
    long aOff,
    const unsigned short* __restrict__ Bh, const unsigned short* __restrict__ Bl,
    unsigned short* __restrict__ Oh, unsigned short* __restrict__ Ol,
    float* __restrict__ part)
{
    const int N = 4096;
    int t = threadIdx.x;
    int lane = t & 63, w = t >> 6;
    int mg = w >> 1, ng = w & 1;
    int b = blockIdx.x >> 7;
    int tile = blockIdx.x & 127;
    int ncol = tile * 32 + ng * 16 + (lane & 15);
    int kq = (lane >> 4) << 3;

    f32x4 accP[2][3] = {};
    f32x4 accD[2][3] = {};
    const unsigned short* AhB = Aph + aOff;
    const unsigned short* AlB = Apl + aOff;

#pragma unroll
    for (int ks = 0; ks < 4; ++ks) {
        short8 bh[3], bl[3];
#pragma unroll
        for (int c = 0; c < 3; ++c) {
            long boff = ((long)(b * 3 + c) * N + ncol) * 128 + ks * 32 + kq;
            bh[c] = *(const short8*)(Bh + boff);
            bl[c] = *(const short8*)(Bl + boff);
        }
#pragma unroll
        for (int pi = 0; pi < 2; ++pi) {
            int mf = 2 * mg + pi;
            long aoffP = (((long)ks * 16 + mf) * 64 + lane) * 8;
            short8 ahP = *(const short8*)(AhB + aoffP);
            short8 alP = *(const short8*)(AlB + aoffP);
#pragma unroll
            for (int c = 0; c < 3; ++c) {
                accP[pi][c] = __builtin_amdgcn_mfma_f32_16x16x32_bf16(ahP, bh[c], accP[pi][c], 0, 0, 0);
                accP[pi][c] = __builtin_amdgcn_mfma_f32_16x16x32_bf16(ahP, bl[c], accP[pi][c], 0, 0, 0);
                accP[pi][c] = __builtin_amdgcn_mfma_f32_16x16x32_bf16(alP, bh[c], accP[pi][c], 0, 0, 0);
            }
            long aoffD = (((long)ks * 16 + (8 + mf)) * 64 + lane) * 8;
            short8 ahD = *(const short8*)(AhB + aoffD);
            short8 alD = *(const short8*)(AlB + aoffD);
#pragma unroll
            for (int c = 0; c < 3; ++c) {
                accD[pi][c] = __builtin_amdgcn_mfma_f32_16x16x32_bf16(ahD, bh[c], accD[pi][c], 0, 0, 0);
                accD[pi][c] = __builtin_amdgcn_mfma_f32_16x16x32_bf16(ahD, bl[c], accD[pi][c], 0, 0, 0);
                accD[pi][c] = __builtin_amdgcn_mfma_f32_16x16x32_bf16(alD, bh[c], accD[pi][c], 0, 0, 0);
            }
        }
    }

#pragma unroll
    for (int pi = 0; pi < 2; ++pi) {
        int obase = 32 * mg + 16 * pi + ((lane >> 4) << 2);
        float Pv[3][4];
#pragma unroll
        for (int r = 0; r < 4; ++r) {
            float P[3], D[3];
#pragma unroll
            for (int c = 0; c < 3; ++c) { P[c] = accP[pi][c][r]; D[c] = accD[pi][c][r]; }
            float dot = P[0] * D[0] + P[1] * D[1] + P[2] * D[2];
            float dsq = D[0] * D[0] + D[1] * D[1] + D[2] * D[2];
            if (dot < 0.0f) {
                float s = dot / (dsq + 1e-6f);
                P[0] -= s * D[0]; P[1] -= s * D[1]; P[2] -= s * D[2];
            }
            Pv[0][r] = P[0]; Pv[1][r] = P[1]; Pv[2][r] = P[2];
        }
#pragma unroll
        for (int c = 0; c < 3; ++c) {
            unsigned short hs[4], ls[4];
#pragma unroll
            for (int r = 0; r < 4; ++r) {
                hs[r] = f2bf(Pv[c][r]);
                ls[r] = f2bf(Pv[c][r] - bf2f(hs[r]));
            }
            long ooff = ((long)(b * 3 + c) * N + ncol) * 128 + obase;
            *(ushort4*)(Oh + ooff) = make_ushort4(hs[0], hs[1], hs[2], hs[3]);
            *(ushort4*)(Ol + ooff) = make_ushort4(ls[0], ls[1], ls[2], ls[3]);
        }
#pragma unroll
        for (int c = 0; c < 3; ++c) {
#pragma unroll
            for (int r = 0; r < 4; ++r) {
                float v = Pv[c][r];
                v += __shfl_xor(v, 1);
                v += __shfl_xor(v, 2);
                v += __shfl_xor(v, 4);
                v += __shfl_xor(v, 8);
                if ((lane & 15) == 0)
                    part[((long)(b * 3 + c) * 256 + tile * 2 + ng) * 128 + (obase + r)] = v;
            }
        }
    }
}

// ---------------- fused: y2 = LNA(Wg y1+bP, Ug y1+bD) [LDS] -> Wout -> out1;
//                  if HASNEXT: y1' = LNA(Wl' y2, Ul' y2) -> y1 + yg partials ----------------
template<bool HASNEXT>
__global__ __launch_bounds__(512, 1) void fused_kernel(
    const unsigned short* __restrict__ Aph, const unsigned short* __restrict__ Apl,
    long aOffG, long aOffOut, long aOffNext,
    unsigned short* __restrict__ y1h, unsigned short* __restrict__ y1l,
    const float* __restrict__ biasP, const float* __restrict__ biasD,
    float* __restrict__ Ofp, float* __restrict__ part, int accum)
{
    const int N = 4096;
    __shared__ unsigned short ylds[2][3][2][2048];   // 48 KB
    int t = threadIdx.x;
    int lane = t & 63, w = t >> 6;
    int mg = w >> 1, ng = w & 1;
    int b = blockIdx.x >> 7;
    int tile = blockIdx.x & 127;
    int ncol = tile * 32 + ng * 16 + (lane & 15);
    int kq = (lane >> 4) << 3;

    // ---------- phase 1: y2 = LNA(Wg y1 + biasP, Ug y1 + biasD) -> ylds ----------
    {
        f32x4 accP[2][3] = {};
        f32x4 accD[2][3] = {};
        const unsigned short* AhB = Aph + aOffG;
        const unsigned short* AlB = Apl + aOffG;
#pragma unroll
        for (int ks = 0; ks < 4; ++ks) {
            short8 bh[3], bl[3];
#pragma unroll
            for (int c = 0; c < 3; ++c) {
                long boff = ((long)(b * 3 + c) * N + ncol) * 128 + ks * 32 + kq;
                bh[c] = *(const short8*)(y1h + boff);
                bl[c] = *(const short8*)(y1l + boff);
            }
#pragma unroll
            for (int pi = 0; pi < 2; ++pi) {
                int mf = 2 * mg + pi;
                long aoffP = (((long)ks * 16 + mf) * 64 + lane) * 8;
                short8 ahP = *(const short8*)(AhB + aoffP);
                short8 alP = *(const short8*)(AlB + aoffP);
#pragma unroll
                for (int c = 0; c < 3; ++c) {
                    accP[pi][c] = __builtin_amdgcn_mfma_f32_16x16x32_bf16(ahP, bh[c], accP[pi][c], 0, 0, 0);
                    accP[pi][c] = __builtin_amdgcn_mfma_f32_16x16x32_bf16(ahP, bl[c], accP[pi][c], 0, 0, 0);
                    accP[pi][c] = __builtin_amdgcn_mfma_f32_16x16x32_bf16(alP, bh[c], accP[pi][c], 0, 0, 0);
                }
                long aoffD = (((long)ks * 16 + (8 + mf)) * 64 + lane) * 8;
                short8 ahD = *(const short8*)(AhB + aoffD);
                short8 alD = *(const short8*)(AlB + aoffD);
#pragma unroll
                for (int c = 0; c < 3; ++c) {
                    accD[pi][c] = __builtin_amdgcn_mfma_f32_16x16x32_bf16(ahD, bh[c], accD[pi][c], 0, 0, 0);
                    accD[pi][c] = __builtin_amdgcn_mfma_f32_16x16x32_bf16(ahD, bl[c], accD[pi][c], 0, 0, 0);
                    accD[pi][c] = __builtin_amdgcn_mfma_f32_16x16x32_bf16(alD, bh[c], accD[pi][c], 0, 0, 0);
                }
            }
        }
#pragma unroll
        for (int pi = 0; pi < 2; ++pi) {
            int obase = 32 * mg + 16 * pi + ((lane >> 4) << 2);
            float Pv[3][4];
#pragma unroll
            for (int r = 0; r < 4; ++r) {
                int o = obase + r;
                float P[3], D[3];
#pragma unroll
                for (int c = 0; c < 3; ++c) {
                    long bb = ((long)(b * 128 + o)) * 3 + c;
                    P[c] = accP[pi][c][r] + biasP[bb];
                    D[c] = accD[pi][c][r] + biasD[bb];
                }
                float dot = P[0] * D[0] + P[1] * D[1] + P[2] * D[2];
                float dsq = D[0] * D[0] + D[1] * D[1] + D[2] * D[2];
                if (dot < 0.0f) {
                    float s = dot / (dsq + 1e-6f);
                    P[0] -= s * D[0]; P[1] -= s * D[1]; P[2] -= s * D[2];
                }
                Pv[0][r] = P[0]; Pv[1][r] = P[1]; Pv[2][r] = P[2];
            }
#pragma unroll
            for (int c = 0; c < 3; ++c) {
                unsigned short hs[4], ls[4];
#pragma unroll
                for (int r = 0; r < 4; ++r) {
                    hs[r] = f2bf(Pv[c][r]);
                    ls[r] = f2bf(Pv[c][r] - bf2f(hs[r]));
                }
                int li = ((obase >> 3) << 7) + ((lane & 15) << 3) + (obase & 7);
                *(ushort4*)&ylds[ng][c][0][li] = make_ushort4(hs[0], hs[1], hs[2], hs[3]);
                *(ushort4*)&ylds[ng][c][1][li] = make_ushort4(ls[0], ls[1], ls[2], ls[3]);
            }
        }
    }
    __syncthreads();

    // ---------- phase 2: out1 (+)= Wout_l @ y2 ----------
    {
        f32x4 accO[2][3] = {};
        const unsigned short* AoH = Aph + aOffOut;
        const unsigned short* AoL = Apl + aOffOut;
#pragma unroll
        for (int ks = 0; ks < 4; ++ks) {
            short8 yh[3], yl[3];
            int li = (((ks << 2) + (lane >> 4)) << 7) + ((lane & 15) << 3);
#pragma unroll
            for (int c = 0; c < 3; ++c) {
                yh[c] = *(const short8*)&ylds[ng][c][0][li];
                yl[c] = *(const short8*)&ylds[ng][c][1][li];
            }
#pragma unroll
            for (int pi = 0; pi < 2; ++pi) {
                int mf = 2 * mg + pi;
                long aoff = (((long)ks * 8 + mf) * 64 + lane) * 8;
                short8 ah = *(const short8*)(AoH + aoff);
                short8 al = *(const short8*)(AoL + aoff);
#pragma unroll
                for (int c = 0; c < 3; ++c) {
                    accO[pi][c] = __builtin_amdgcn_mfma_f32_16x16x32_bf16(ah, yh[c], accO[pi][c], 0, 0, 0);
                    accO[pi][c] = __builtin_amdgcn_mfma_f32_16x16x32_bf16(ah, yl[c], accO[pi][c], 0, 0, 0);
                    accO[pi][c] = __builtin_amdgcn_mfma_f32_16x16x32_bf16(al, yh[c], accO[pi][c], 0, 0, 0);
                }
            }
        }
#pragma unroll
        for (int pi = 0; pi < 2; ++pi) {
            int obase = 32 * mg + 16 * pi + ((lane >> 4) << 2);
#pragma unroll
            for (int r = 0; r < 4; ++r) {
                int o = obase + r;
#pragma unroll
                for (int c = 0; c < 3; ++c) {
                    long off = ((long)(b * 128 + o) * 3 + c) * N + ncol;
                    float v = accO[pi][c][r];
                    if (accum) v += Ofp[off];
                    Ofp[off] = v;
                }
            }
        }
    }

    // ---------- phase 3 (HASNEXT): y1' = LNA(Wl' y2, Ul' y2) -> y1 + yg partials ----------
    if (HASNEXT) {
        f32x4 accP[2][3] = {};
        f32x4 accD[2][3] = {};
        const unsigned short* AnH = Aph + aOffNext;
        const unsigned short* AnL = Apl + aOffNext;
#pragma unroll
        for (int ks = 0; ks < 4; ++ks) {
            short8 bh[3], bl[3];
            int li = (((ks << 2) + (lane >> 4)) << 7) + ((lane & 15) << 3);
#pragma unroll
            for (int c = 0; c < 3; ++c) {
                bh[c] = *(const short8*)&ylds[ng][c][0][li];
                bl[c] = *(const short8*)&ylds[ng][c][1][li];
            }
#pragma unroll
            for (int pi = 0; pi < 2; ++pi) {
                int mf = 2 * mg + pi;
                long aoffP = (((long)ks * 16 + mf) * 64 + lane) * 8;
                short8 ahP = *(const short8*)(AnH + aoffP);
                short8 alP = *(const short8*)(AnL + aoffP);
#pragma unroll
                for (int c = 0; c < 3; ++c) {
                    accP[pi][c] = __builtin_amdgcn_mfma_f32_16x16x32_bf16(ahP, bh[c], accP[pi][c], 0, 0, 0);
                    accP[pi][c] = __builtin_amdgcn_mfma_f32_16x16x32_bf16(ahP, bl[c], accP[pi][c], 0, 0, 0);
                    accP[pi][c] = __builtin_amdgcn_mfma_f32_16x16x32_bf16(alP, bh[c], accP[pi][c], 0, 0, 0);
                }
                long aoffD = (((long)ks * 16 + (8 + mf)) * 64 + lane) * 8;
                short8 ahD = *(const short8*)(AnH + aoffD);
                short8 alD = *(const short8*)(AnL + aoffD);
#pragma unroll
                for (int c = 0; c < 3; ++c) {
                    accD[pi][c] = __builtin_amdgcn_mfma_f32_16x16x32_bf16(ahD, bh[c], accD[pi][c], 0, 0, 0);
                    accD[pi][c] = __builtin_amdgcn_mfma_f32_16x16x32_bf16(ahD, bl[c], accD[pi][c], 0, 0, 0);
                    accD[pi][c] = __builtin_amdgcn_mfma_f32_16x16x32_bf16(alD, bh[c], accD[pi][c], 0, 0, 0);
                }
            }
        }
#pragma unroll
        for (int pi = 0; pi < 2; ++pi) {
            int obase = 32 * mg + 16 * pi + ((lane >> 4) << 2);
            float Pv[3][4];
#pragma unroll
            for (int r = 0; r < 4; ++r) {
                float P[3], D[3];
#pragma unroll
                for (int c = 0; c < 3; ++c) { P[c] = accP[pi][c][r]; D[c] = accD[pi][c][r]; }
                float dot = P[0] * D[0] + P[1] * D[1] + P[2] * D[2];
                float dsq = D[0] * D[0] + D[1] * D[1] + D[2] * D[2];
                if (dot < 0.0f) {
                    float s = dot / (dsq + 1e-6f);
                    P[0] -= s * D[0]; P[1] -= s * D[1]; P[2] -= s * D[2];
                }
                Pv[0][r] = P[0]; Pv[1][r] = P[1]; Pv[2][r] = P[2];
            }
#pragma unroll
            for (int c = 0; c < 3; ++c) {
                unsigned short hs[4], ls[4];
#pragma unroll
                for (int r = 0; r < 4; ++r) {
                    hs[r] = f2bf(Pv[c][r]);
                    ls[r] = f2bf(Pv[c][r] - bf2f(hs[r]));
                }
                long ooff = ((long)(b * 3 + c) * N + ncol) * 128 + obase;
                *(ushort4*)(y1h + ooff) = make_ushort4(hs[0], hs[1], hs[2], hs[3]);
                *(ushort4*)(y1l + ooff) = make_ushort4(ls[0], ls[1], ls[2], ls[3]);
            }
#pragma unroll
            for (int c = 0; c < 3; ++c) {
#pragma unroll
                for (int r = 0; r < 4; ++r) {
                    float v = Pv[c][r];
                    v += __shfl_xor(v, 1);
                    v += __shfl_xor(v, 2);
                    v += __shfl_xor(v, 4);
                    v += __shfl_xor(v, 8);
                    if ((lane & 15) == 0)
                        part[((long)(b * 3 + c) * 256 + tile * 2 + ng) * 128 + (obase + r)] = v;
                }
            }
        }
    }
}

// ---------------- fused yg reduce + bias: 6 blocks (b*3+c), 1024 threads ----------------
__global__ __launch_bounds__(1024) void ygredbias_kernel(const float* __restrict__ part,
                                                         const float* __restrict__ Wg,
                                                         const float* __restrict__ Ug,
                                                         float* __restrict__ biasP,
                                                         float* __restrict__ biasD) {
    __shared__ float red[8][128];
    __shared__ float ygs[128];
    int bc = blockIdx.x;
    int t = threadIdx.x;
    int o = t & 127, g = t >> 7;
    float s = 0.f;
    for (int seg = g * 32; seg < g * 32 + 32; ++seg)
        s += part[((long)bc * 256 + seg) * 128 + o];
    red[g][o] = s;
    __syncthreads();
    if (t < 128) {
        float r = 0.f;
#pragma unroll
        for (int k = 0; k < 8; ++k) r += red[k][t];
        ygs[t] = r * (1.0f / 4096.0f);
    }
    __syncthreads();
    if (t < 256) {
        int oo = t & 127; bool isD = t >= 128;
        const float* row = (isD ? Ug : Wg) + oo * 256 + 128;
        float s2 = 0.f;
        for (int i = 0; i < 128; ++i) s2 = fmaf(row[i], ygs[i], s2);
        int b = bc / 3, c = bc % 3;
        (isD ? biasD : biasP)[((long)(b * 128 + oo)) * 3 + c] = s2;
    }
}

// ---------------- mean over N per (b, o, c) row of fp32 out1 ----------------
__global__ __launch_bounds__(256) void reduce_mean_kernel(const float* __restrict__ src, long bs,
                                                          float* __restrict__ dst, int N) {
    __shared__ float red[256];
    int row = blockIdx.x;
    int b = row / 384; int rr = row % 384;
    const float* p = src + (long)b * bs + (long)rr * N;
    float s = 0.f;
    for (int i = threadIdx.x; i < N; i += 256) s += p[i];
    red[threadIdx.x] = s;
    __syncthreads();
    for (int st = 128; st > 0; st >>= 1) {
        if (threadIdx.x < st) red[threadIdx.x] += red[threadIdx.x + st];
        __syncthreads();
    }
    if (threadIdx.x == 0) dst[row] = red[0] / (float)N;
}

extern "C" void kernel_launch(void* const* d_in, const int* in_sizes, int n_in,
                              void* d_out, int out_size, void* d_ws, size_t ws_size,
                              hipStream_t stream) {
    const float* x    = (const float*)d_in[0];
    const float* Win  = (const float*)d_in[1];
    const float* Uin  = (const float*)d_in[2];
    const float* Wl   = (const float*)d_in[3];
    const float* Ul   = (const float*)d_in[4];
    const float* Wg   = (const float*)d_in[5];
    const float* Ug   = (const float*)d_in[6];
    const float* Wout = (const float*)d_in[7];

    const int B = 2, N = 4096, H = 128;
    float* out0 = (float*)d_out;                 // (B,128,3) mean
    float* out1 = out0 + (long)B * H * 3;        // (B,128,3,N) fp32

    float* ws = (float*)d_ws;
    long off = 0;
    float4* pts4 = (float4*)ws;                  off += (long)B * N * 4;
    int* idx = (int*)(ws + off);                 off += (long)B * N * 16;
    const long ACT = (long)B * 3 * N * H;        // ushort count
    unsigned short* f0h = (unsigned short*)(ws + off);  off += ACT / 2;
    unsigned short* f0l = (unsigned short*)(ws + off);  off += ACT / 2;
    unsigned short* y1h = (unsigned short*)(ws + off);  off += ACT / 2;
    unsigned short* y1l = (unsigned short*)(ws + off);  off += ACT / 2;
    unsigned short* Aph = (unsigned short*)(ws + off);  off += 327680 / 2;
    unsigned short* Apl = (unsigned short*)(ws + off);  off += 327680 / 2;
    float* part  = ws + off;                     off += 6L * 256 * 128;
    float* biasP = ws + off;                     off += B * H * 3;
    float* biasD = ws + off;                     off += B * H * 3;
    // ~27.6 MB of workspace

    long bs128 = (long)H * 3 * N;

    setup_kernel<<<1280, 256, 0, stream>>>(x, pts4, Wl, Ul, Wg, Ug, Wout, Aph, Apl, N, B);
    knn_kernel<<<B * (N / 16), 1024, 0, stream>>>(pts4, idx, N);
    edge_kernel<<<B * (N / 8), 256, 0, stream>>>(pts4, idx, Win, Uin, f0h, f0l, N);

    // layer-0 input GEMM: y1 = LNA(Wl0 f0, Ul0 f0) + yg partials
    gemm0_kernel<<<256, 512, 0, stream>>>(Aph, Apl, 0L, f0h, f0l, y1h, y1l, part);

    for (int l = 0; l < 4; ++l) {
        ygredbias_kernel<<<6, 1024, 0, stream>>>(part,
            Wg + (long)l * H * 256, Ug + (long)l * H * 256, biasP, biasD);
        long aG = (long)(4 + l) * 32768;
        long aO = 262144 + (long)l * 16384;
        if (l < 3) {
            fused_kernel<true><<<256, 512, 0, stream>>>(
                Aph, Apl, aG, aO, (long)(l + 1) * 32768,
                y1h, y1l, biasP, biasD, out1, part, l > 0 ? 1 : 0);
        } else {
            fused_kernel<false><<<256, 512, 0, stream>>>(
                Aph, Apl, aG, aO, 0L,
                y1h, y1l, biasP, biasD, out1, part, 1);
        }
    }
    reduce_mean_kernel<<<B * H * 3, 256, 0, stream>>>(out1, bs128, out0, N);
}

// Round 12
// 276.107 us; speedup vs baseline: 1.2761x; 1.0307x over previous
//
#include <hip/hip_runtime.h>
#include <hip/hip_bf16.h>
#include <cfloat>

// VecPointNet on MI355X, round 12:
//  - Base = r11 (284.6us, best). Single change: kNN insert chain rebuilt on
//    DPP row_shr:1 (1-cy VALU lane shift, list lives in DPP row 0) + readlane
//    (SGPR broadcast) instead of ds_bpermute-based __shfl/__shfl_up.
//    Qual test relaxed to u <= Tu (equal-key/larger-idx admits are no-op
//    inserts under strict-lex insertion -> top_k tie semantics preserved).

typedef __attribute__((ext_vector_type(8))) short short8;
typedef __attribute__((ext_vector_type(4))) float f32x4;

__device__ __forceinline__ unsigned short f2bf(float f) {
    union { float f; unsigned u; } v; v.f = f;
    unsigned r = v.u + 0x7fffu + ((v.u >> 16) & 1u);
    return (unsigned short)(r >> 16);
}
__device__ __forceinline__ float bf2f(unsigned short h) {
    union { unsigned u; float f; } v; v.u = ((unsigned)h) << 16;
    return v.f;
}

// ---------------- setup: prep (pts4) + weight pack ----------------
__global__ __launch_bounds__(256) void setup_kernel(const float* __restrict__ x,
                                                    float4* __restrict__ pts4,
                                                    const float* __restrict__ Wl,
                                                    const float* __restrict__ Ul,
                                                    const float* __restrict__ Wg,
                                                    const float* __restrict__ Ug,
                                                    const float* __restrict__ Wout,
                                                    unsigned short* __restrict__ Ah,
                                                    unsigned short* __restrict__ Al,
                                                    int N, int B) {
    int t = blockIdx.x * 256 + threadIdx.x;     // 0..327679
    if (t < B * N) {
        int b = t / N, n = t - b * N;
        const float* xb = x + (long)b * 3 * N;
        float px = xb[n], py = xb[N + n], pz = xb[2 * N + n];
        pts4[t] = make_float4(px, py, pz, px * px + py * py + pz * pz);
    }
    int g, r, M; long base;
    if (t < 262144) { g = t >> 15; r = t & 32767; M = 256; base = (long)g << 15; }
    else { int t2 = t - 262144; g = 8 + (t2 >> 14); r = t2 & 16383; M = 128;
           base = 262144 + (long)(g - 8) * 16384; }
    int MF = M >> 4;
    int ks = r / (MF * 512);
    int mf = (r >> 9) % MF;
    int lane = (r >> 3) & 63;
    int j = r & 7;
    int m = mf * 16 + (lane & 15);
    int k = ks * 32 + ((lane >> 4) << 3) + j;
    const float* src; int ldw; int row;
    if (g < 4) {
        ldw = 128; row = m & 127;
        src = (m < 128) ? (Wl + (long)g * 128 * 128) : (Ul + (long)g * 128 * 128);
    } else if (g < 8) {
        ldw = 256; row = m & 127;
        int l = g - 4;
        src = (m < 128) ? (Wg + (long)l * 128 * 256) : (Ug + (long)l * 128 * 256);
    } else {
        ldw = 512; row = m;
        src = Wout + (g - 8) * 128;
    }
    float v = src[(long)row * ldw + k];
    unsigned short h = f2bf(v);
    Ah[base + r] = h;
    Al[base + r] = f2bf(v - bf2f(h));
}

// ---------------- knn: wave/query, stale-T inserts via DPP + readlane ----------------
// Sorted (u,idx) lex-ascending list in lanes 0..15 (DPP row 0). T = lane15 key,
// refreshed once per 64-chunk (stale T only over-admits; non-qualifying inserts
// are no-ops under strict-lex insertion). Exact jax.lax.top_k tie semantics.
__global__ __launch_bounds__(1024) void knn_kernel(const float4* __restrict__ pts4,
                                                   int* __restrict__ idxOut, int N) {
    __shared__ float4 cbuf[4096];   // 64 KB
    int t = threadIdx.x;
    int tilesPerB = N / 16;
    int b = blockIdx.x / tilesPerB;
    int q = (blockIdx.x % tilesPerB) * 16 + (t >> 6);
    int lane = t & 63;

    for (int i = t; i < N; i += 1024) cbuf[i] = pts4[b * N + i];
    __syncthreads();

    float4 Q = cbuf[q];
    unsigned ku = 0xFFFFFFFFu; int ki = 0x7fffffff;   // lanes 0..15: sorted list
    unsigned Tu = 0xFFFFFFFFu;                        // stale 16th-best key

    for (int c0 = 0; c0 < N; c0 += 64) {
        float4 C = cbuf[c0 + lane];
        float dot = Q.x * C.x + Q.y * C.y + Q.z * C.z;
        float d2 = Q.w + C.w - 2.0f * dot;            // same formula as reference
        unsigned u = __float_as_uint(d2);
        u ^= (unsigned)((int)u >> 31) | 0x80000000u;  // orderable uint
        int ci = c0 + lane;
        unsigned long long mask = __ballot(u <= Tu);
        while (mask) {
            int src = __ffsll(mask) - 1;
            mask &= mask - 1;
            unsigned vu = (unsigned)__builtin_amdgcn_readlane((int)u, src);
            int      vi = __builtin_amdgcn_readlane(ci, src);
            // k[lane-1] via DPP row_shr:1 (lanes 0..15 are one DPP row)
            unsigned kum1 = (unsigned)__builtin_amdgcn_update_dpp(
                                (int)ku, (int)ku, 0x111, 0xF, 0xF, false);
            int      kim1 = __builtin_amdgcn_update_dpp(
                                ki, ki, 0x111, 0xF, 0xF, false);
            if (lane == 0) { kum1 = 0u; kim1 = (-2147483647 - 1); }
            bool lem1 = (vu < kum1) || (vu == kum1 && vi < kim1);  // v < k[j-1]
            bool ltj  = (vu < ku)   || (vu == ku   && vi < ki);    // v < k[j]
            unsigned knu = lem1 ? kum1 : (ltj ? vu : ku);
            int      kni = lem1 ? kim1 : (ltj ? vi : ki);
            if (lane < 16) { ku = knu; ki = kni; }
        }
        Tu = (unsigned)__builtin_amdgcn_readlane((int)ku, 15);
    }
    if (lane < 16) idxOut[(b * N + q) * 16 + lane] = ki;
}

// ---------------- edge features + input LNA + mean over K -> f0 bf16 hi/lo ----------------
__global__ __launch_bounds__(256) void edge_kernel(const float4* __restrict__ pts4,
                                                   const int* __restrict__ idx,
                                                   const float* __restrict__ Win,
                                                   const float* __restrict__ Uin,
                                                   unsigned short* __restrict__ Yh,
                                                   unsigned short* __restrict__ Yl,
                                                   int N) {
    __shared__ float4 nbuf[8][16];
    __shared__ float4 cpt[8];
    int nTiles = N / 8;
    int b = blockIdx.x / nTiles;
    int n0 = (blockIdx.x % nTiles) * 8;
    int t = threadIdx.x;
    if (t < 128) {
        int pl = t >> 4, k = t & 15;
        int nb = idx[(b * N + n0 + pl) * 16 + k];
        nbuf[pl][k] = pts4[b * N + nb];
    } else if (t < 136) {
        cpt[t - 128] = pts4[b * N + n0 + (t - 128)];
    }
    __syncthreads();
    int o = t & 127, h = t >> 7;
    float w0 = Win[o * 3], w1 = Win[o * 3 + 1], w2 = Win[o * 3 + 2];
    float u0 = Uin[o * 3], u1 = Uin[o * 3 + 1], u2 = Uin[o * 3 + 2];
    for (int pl = h * 4; pl < h * 4 + 4; ++pl) {
        float4 c4 = cpt[pl];
        float inv = 1.0f / fmaxf(sqrtf(c4.w), 1e-12f);
        float ax = c4.x * inv, ay = c4.y * inv, az = c4.z * inv;
        float a0 = 0.f, a1 = 0.f, a2 = 0.f;
        for (int k = 0; k < 16; ++k) {
            float4 nb = nbuf[pl][k];
            float cr0 = ay * nb.z - az * nb.y;
            float cr1 = az * nb.x - ax * nb.z;
            float cr2 = ax * nb.y - ay * nb.x;
            float df0 = nb.x - c4.x, df1 = nb.y - c4.y, df2 = nb.z - c4.z;
            float P0 = w0 * cr0 + w1 * df0 + w2 * c4.x;
            float P1 = w0 * cr1 + w1 * df1 + w2 * c4.y;
            float P2 = w0 * cr2 + w1 * df2 + w2 * c4.z;
            float D0 = u0 * cr0 + u1 * df0 + u2 * c4.x;
            float D1 = u0 * cr1 + u1 * df1 + u2 * c4.y;
            float D2 = u0 * cr2 + u1 * df2 + u2 * c4.z;
            float dot = P0 * D0 + P1 * D1 + P2 * D2;
            float dsq = D0 * D0 + D1 * D1 + D2 * D2;
            if (dot < 0.0f) {
                float s = dot / (dsq + 1e-6f);
                P0 -= s * D0; P1 -= s * D1; P2 -= s * D2;
            }
            a0 += P0; a1 += P1; a2 += P2;
        }
        float vals[3] = { a0 * (1.0f / 16.0f), a1 * (1.0f / 16.0f), a2 * (1.0f / 16.0f) };
        long n = n0 + pl;
#pragma unroll
        for (int c = 0; c < 3; ++c) {
            long off = ((long)(b * 3 + c) * 4096 + n) * 128 + o;
            unsigned short hh = f2bf(vals[c]);
            Yh[off] = hh;
            Yl[off] = f2bf(vals[c] - bf2f(hh));
        }
    }
}

// ---------------- gemm0: y1 = LNA(Wl0 f0, Ul0 f0) + yg partials ----------------
__global__ __launch_bounds__(512, 1) void gemm0_kernel(
    const unsigned short* __restrict__ Aph, const unsigned short* __restrict__ Apl,
    long aOff,
    const unsigned short* __restrict__ Bh, const unsigned short* __restrict__ Bl,
    unsigned short* __restrict__ Oh, unsigned short* __restrict__ Ol,
    float* __restrict__ part)
{
    const int N = 4096;
    int t = threadIdx.x;
    int lane = t & 63, w = t >> 6;
    int mg = w >> 1, ng = w & 1;
    int b = blockIdx.x >> 7;
    int tile = blockIdx.x & 127;
    int ncol = tile * 32 + ng * 16 + (lane & 15);
    int kq = (lane >> 4) << 3;

    f32x4 accP[2][3] = {};
    f32x4 accD[2][3] = {};
    const unsigned short* AhB = Aph + aOff;
    const unsigned short* AlB = Apl + aOff;

#pragma unroll
    for (int ks = 0; ks < 4; ++ks) {
        short8 bh[3], bl[3];
#pragma unroll
        for (int c = 0; c < 3; ++c) {
            long boff = ((long)(b * 3 + c) * N + ncol) * 128 + ks * 32 + kq;
            bh[c] = *(const short8*)(Bh + boff);
            bl[c] = *(const short8*)(Bl + boff);
        }
#pragma unroll
        for (int pi = 0; pi < 2; ++pi) {
            int mf = 2 * mg + pi;
            long aoffP = (((long)ks * 16 + mf) * 64 + lane) * 8;
            short8 ahP = *(const short8*)(AhB + aoffP);
            short8 alP = *(const short8*)(AlB + aoffP);
#pragma unroll
            for (int c = 0; c < 3; ++c) {
                accP[pi][c] = __builtin_amdgcn_mfma_f32_16x16x32_bf16(ahP, bh[c], accP[pi][c], 0, 0, 0);
                accP[pi][c] = __builtin_amdgcn_mfma_f32_16x16x32_bf16(ahP, bl[c], accP[pi][c], 0, 0, 0);
                accP[pi][c] = __builtin_amdgcn_mfma_f32_16x16x32_bf16(alP, bh[c], accP[pi][c], 0, 0, 0);
            }
            long aoffD = (((long)ks * 16 + (8 + mf)) * 64 + lane) * 8;
            short8 ahD = *(const short8*)(AhB + aoffD);
            short8 alD = *(const short8*)(AlB + aoffD);
#pragma unroll
            for (int c = 0; c < 3; ++c) {
                accD[pi][c] = __builtin_amdgcn_mfma_f32_16x16x32_bf16(ahD, bh[c], accD[pi][c], 0, 0, 0);
                accD[pi][c] = __builtin_amdgcn_mfma_f32_16x16x32_bf16(ahD, bl[c], accD[pi][c], 0, 0, 0);
                accD[pi][c] = __builtin_amdgcn_mfma_f32_16x16x32_bf16(alD, bh[c], accD[pi][c], 0, 0, 0);
            }
        }
    }

#pragma unroll
    for (int pi = 0; pi < 2; ++pi) {
        int obase = 32 * mg + 16 * pi + ((lane >> 4) << 2);
        float Pv[3][4];
#pragma unroll
        for (int r = 0; r < 4; ++r) {
            float P[3], D[3];
#pragma unroll
            for (int c = 0; c < 3; ++c) { P[c] = accP[pi][c][r]; D[c] = accD[pi][c][r]; }
            float dot = P[0] * D[0] + P[1] * D[1] + P[2] * D[2];
            float dsq = D[0] * D[0] + D[1] * D[1] + D[2] * D[2];
            if (dot < 0.0f) {
                float s = dot / (dsq + 1e-6f);
                P[0] -= s * D[0]; P[1] -= s * D[1]; P[2] -= s * D[2];
            }
            Pv[0][r] = P[0]; Pv[1][r] = P[1]; Pv[2][r] = P[2];
        }
#pragma unroll
        for (int c = 0; c < 3; ++c) {
            unsigned short hs[4], ls[4];
#pragma unroll
            for (int r = 0; r < 4; ++r) {
                hs[r] = f2bf(Pv[c][r]);
                ls[r] = f2bf(Pv[c][r] - bf2f(hs[r]));
            }
            long ooff = ((long)(b * 3 + c) * N + ncol) * 128 + obase;
            *(ushort4*)(Oh + ooff) = make_ushort4(hs[0], hs[1], hs[2], hs[3]);
            *(ushort4*)(Ol + ooff) = make_ushort4(ls[0], ls[1], ls[2], ls[3]);
        }
#pragma unroll
        for (int c = 0; c < 3; ++c) {
#pragma unroll
            for (int r = 0; r < 4; ++r) {
                float v = Pv[c][r];
                v += __shfl_xor(v, 1);
                v += __shfl_xor(v, 2);
                v += __shfl_xor(v, 4);
                v += __shfl_xor(v, 8);
                if ((lane & 15) == 0)
                    part[((long)(b * 3 + c) * 256 + tile * 2 + ng) * 128 + (obase + r)] = v;
            }
        }
    }
}

// ---------------- fused: y2 = LNA(Wg y1+bP, Ug y1+bD) [LDS] -> Wout -> out1;
//                  if HASNEXT: y1' = LNA(Wl' y2, Ul' y2) -> y1 + yg partials ----------------
template<bool HASNEXT>
__global__ __launch_bounds__(512, 1) void fused_kernel(
    const unsigned short* __restrict__ Aph, const unsigned short* __restrict__ Apl,
    long aOffG, long aOffOut, long aOffNext,
    unsigned short* __restrict__ y1h, unsigned short* __restrict__ y1l,
    const float* __restrict__ biasP, const float* __restrict__ biasD,
    float* __restrict__ Ofp, float* __restrict__ part, int accum)
{
    const int N = 4096;
    __shared__ unsigned short ylds[2][3][2][2048];   // 48 KB
    int t = threadIdx.x;
    int lane = t & 63, w = t >> 6;
    int mg = w >> 1, ng = w & 1;
    int b = blockIdx.x >> 7;
    int tile = blockIdx.x & 127;
    int ncol = tile * 32 + ng * 16 + (lane & 15);
    int kq = (lane >> 4) << 3;

    // ---------- phase 1: y2 = LNA(Wg y1 + biasP, Ug y1 + biasD) -> ylds ----------
    {
        f32x4 accP[2][3] = {};
        f32x4 accD[2][3] = {};
        const unsigned short* AhB = Aph + aOffG;
        const unsigned short* AlB = Apl + aOffG;
#pragma unroll
        for (int ks = 0; ks < 4; ++ks) {
            short8 bh[3], bl[3];
#pragma unroll
            for (int c = 0; c < 3; ++c) {
                long boff = ((long)(b * 3 + c) * N + ncol) * 128 + ks * 32 + kq;
                bh[c] = *(const short8*)(y1h + boff);
                bl[c] = *(const short8*)(y1l + boff);
            }
#pragma unroll
            for (int pi = 0; pi < 2; ++pi) {
                int mf = 2 * mg + pi;
                long aoffP = (((long)ks * 16 + mf) * 64 + lane) * 8;
                short8 ahP = *(const short8*)(AhB + aoffP);
                short8 alP = *(const short8*)(AlB + aoffP);
#pragma unroll
                for (int c = 0; c < 3; ++c) {
                    accP[pi][c] = __builtin_amdgcn_mfma_f32_16x16x32_bf16(ahP, bh[c], accP[pi][c], 0, 0, 0);
                    accP[pi][c] = __builtin_amdgcn_mfma_f32_16x16x32_bf16(ahP, bl[c], accP[pi][c], 0, 0, 0);
                    accP[pi][c] = __builtin_amdgcn_mfma_f32_16x16x32_bf16(alP, bh[c], accP[pi][c], 0, 0, 0);
                }
                long aoffD = (((long)ks * 16 + (8 + mf)) * 64 + lane) * 8;
                short8 ahD = *(const short8*)(AhB + aoffD);
                short8 alD = *(const short8*)(AlB + aoffD);
#pragma unroll
                for (int c = 0; c < 3; ++c) {
                    accD[pi][c] = __builtin_amdgcn_mfma_f32_16x16x32_bf16(ahD, bh[c], accD[pi][c], 0, 0, 0);
                    accD[pi][c] = __builtin_amdgcn_mfma_f32_16x16x32_bf16(ahD, bl[c], accD[pi][c], 0, 0, 0);
                    accD[pi][c] = __builtin_amdgcn_mfma_f32_16x16x32_bf16(alD, bh[c], accD[pi][c], 0, 0, 0);
                }
            }
        }
#pragma unroll
        for (int pi = 0; pi < 2; ++pi) {
            int obase = 32 * mg + 16 * pi + ((lane >> 4) << 2);
            float Pv[3][4];
#pragma unroll
            for (int r = 0; r < 4; ++r) {
                int o = obase + r;
                float P[3], D[3];
#pragma unroll
                for (int c = 0; c < 3; ++c) {
                    long bb = ((long)(b * 128 + o)) * 3 + c;
                    P[c] = accP[pi][c][r] + biasP[bb];
                    D[c] = accD[pi][c][r] + biasD[bb];
                }
                float dot = P[0] * D[0] + P[1] * D[1] + P[2] * D[2];
                float dsq = D[0] * D[0] + D[1] * D[1] + D[2] * D[2];
                if (dot < 0.0f) {
                    float s = dot / (dsq + 1e-6f);
                    P[0] -= s * D[0]; P[1] -= s * D[1]; P[2] -= s * D[2];
                }
                Pv[0][r] = P[0]; Pv[1][r] = P[1]; Pv[2][r] = P[2];
            }
#pragma unroll
            for (int c = 0; c < 3; ++c) {
                unsigned short hs[4], ls[4];
#pragma unroll
                for (int r = 0; r < 4; ++r) {
                    hs[r] = f2bf(Pv[c][r]);
                    ls[r] = f2bf(Pv[c][r] - bf2f(hs[r]));
                }
                int li = ((obase >> 3) << 7) + ((lane & 15) << 3) + (obase & 7);
                *(ushort4*)&ylds[ng][c][0][li] = make_ushort4(hs[0], hs[1], hs[2], hs[3]);
                *(ushort4*)&ylds[ng][c][1][li] = make_ushort4(ls[0], ls[1], ls[2], ls[3]);
            }
        }
    }
    __syncthreads();

    // ---------- phase 2: out1 (+)= Wout_l @ y2 ----------
    {
        f32x4 accO[2][3] = {};
        const unsigned short* AoH = Aph + aOffOut;
        const unsigned short* AoL = Apl + aOffOut;
#pragma unroll
        for (int ks = 0; ks < 4; ++ks) {
            short8 yh[3], yl[3];
            int li = (((ks << 2) + (lane >> 4)) << 7) + ((lane & 15) << 3);
#pragma unroll
            for (int c = 0; c < 3; ++c) {
                yh[c] = *(const short8*)&ylds[ng][c][0][li];
                yl[c] = *(const short8*)&ylds[ng][c][1][li];
            }
#pragma unroll
            for (int pi = 0; pi < 2; ++pi) {
                int mf = 2 * mg + pi;
                long aoff = (((long)ks * 8 + mf) * 64 + lane) * 8;
                short8 ah = *(const short8*)(AoH + aoff);
                short8 al = *(const short8*)(AoL + aoff);
#pragma unroll
                for (int c = 0; c < 3; ++c) {
                    accO[pi][c] = __builtin_amdgcn_mfma_f32_16x16x32_bf16(ah, yh[c], accO[pi][c], 0, 0, 0);
                    accO[pi][c] = __builtin_amdgcn_mfma_f32_16x16x32_bf16(ah, yl[c], accO[pi][c], 0, 0, 0);
                    accO[pi][c] = __builtin_amdgcn_mfma_f32_16x16x32_bf16(al, yh[c], accO[pi][c], 0, 0, 0);
                }
            }
        }
#pragma unroll
        for (int pi = 0; pi < 2; ++pi) {
            int obase = 32 * mg + 16 * pi + ((lane >> 4) << 2);
#pragma unroll
            for (int r = 0; r < 4; ++r) {
                int o = obase + r;
#pragma unroll
                for (int c = 0; c < 3; ++c) {
                    long off = ((long)(b * 128 + o) * 3 + c) * N + ncol;
                    float v = accO[pi][c][r];
                    if (accum) v += Ofp[off];
                    Ofp[off] = v;
                }
            }
        }
    }

    // ---------- phase 3 (HASNEXT): y1' = LNA(Wl' y2, Ul' y2) -> y1 + yg partials ----------
    if (HASNEXT) {
        f32x4 accP[2][3] = {};
        f32x4 accD[2][3] = {};
        const unsigned short* AnH = Aph + aOffNext;
        const unsigned short* AnL = Apl + aOffNext;
#pragma unroll
        for (int ks = 0; ks < 4; ++ks) {
            short8 bh[3], bl[3];
            int li = (((ks << 2) + (lane >> 4)) << 7) + ((lane & 15) << 3);
#pragma unroll
            for (int c = 0; c < 3; ++c) {
                bh[c] = *(const short8*)&ylds[ng][c][0][li];
                bl[c] = *(const short8*)&ylds[ng][c][1][li];
            }
#pragma unroll
            for (int pi = 0; pi < 2; ++pi) {
                int mf = 2 * mg + pi;
                long aoffP = (((long)ks * 16 + mf) * 64 + lane) * 8;
                short8 ahP = *(const short8*)(AnH + aoffP);
                short8 alP = *(const short8*)(AnL + aoffP);
#pragma unroll
                for (int c = 0; c < 3; ++c) {
                    accP[pi][c] = __builtin_amdgcn_mfma_f32_16x16x32_bf16(ahP, bh[c], accP[pi][c], 0, 0, 0);
                    accP[pi][c] = __builtin_amdgcn_mfma_f32_16x16x32_bf16(ahP, bl[c], accP[pi][c], 0, 0, 0);
                    accP[pi][c] = __builtin_amdgcn_mfma_f32_16x16x32_bf16(alP, bh[c], accP[pi][c], 0, 0, 0);
                }
                long aoffD = (((long)ks * 16 + (8 + mf)) * 64 + lane) * 8;
                short8 ahD = *(const short8*)(AnH + aoffD);
                short8 alD = *(const short8*)(AnL + aoffD);
#pragma unroll
                for (int c = 0; c < 3; ++c) {
                    accD[pi][c] = __builtin_amdgcn_mfma_f32_16x16x32_bf16(ahD, bh[c], accD[pi][c], 0, 0, 0);
                    accD[pi][c] = __builtin_amdgcn_mfma_f32_16x16x32_bf16(ahD, bl[c], accD[pi][c], 0, 0, 0);
                    accD[pi][c] = __builtin_amdgcn_mfma_f32_16x16x32_bf16(alD, bh[c], accD[pi][c], 0, 0, 0);
                }
            }
        }
#pragma unroll
        for (int pi = 0; pi < 2; ++pi) {
            int obase = 32 * mg + 16 * pi + ((lane >> 4) << 2);
            float Pv[3][4];
#pragma unroll
            for (int r = 0; r < 4; ++r) {
                float P[3], D[3];
#pragma unroll
                for (int c = 0; c < 3; ++c) { P[c] = accP[pi][c][r]; D[c] = accD[pi][c][r]; }
                float dot = P[0] * D[0] + P[1] * D[1] + P[2] * D[2];
                float dsq = D[0] * D[0] + D[1] * D[1] + D[2] * D[2];
                if (dot < 0.0f) {
                    float s = dot / (dsq + 1e-6f);
                    P[0] -= s * D[0]; P[1] -= s * D[1]; P[2] -= s * D[2];
                }
                Pv[0][r] = P[0]; Pv[1][r] = P[1]; Pv[2][r] = P[2];
            }
#pragma unroll
            for (int c = 0; c < 3; ++c) {
                unsigned short hs[4], ls[4];
#pragma unroll
                for (int r = 0; r < 4; ++r) {
                    hs[r] = f2bf(Pv[c][r]);
                    ls[r] = f2bf(Pv[c][r] - bf2f(hs[r]));
                }
                long ooff = ((long)(b * 3 + c) * N + ncol) * 128 + obase;
                *(ushort4*)(y1h + ooff) = make_ushort4(hs[0], hs[1], hs[2], hs[3]);
                *(ushort4*)(y1l + ooff) = make_ushort4(ls[0], ls[1], ls[2], ls[3]);
            }
#pragma unroll
            for (int c = 0; c < 3; ++c) {
#pragma unroll
                for (int r = 0; r < 4; ++r) {
                    float v = Pv[c][r];
                    v += __shfl_xor(v, 1);
                    v += __shfl_xor(v, 2);
                    v += __shfl_xor(v, 4);
                    v += __shfl_xor(v, 8);
                    if ((lane & 15) == 0)
                        part[((long)(b * 3 + c) * 256 + tile * 2 + ng) * 128 + (obase + r)] = v;
                }
            }
        }
    }
}

// ---------------- fused yg reduce + bias: 6 blocks (b*3+c), 1024 threads ----------------
__global__ __launch_bounds__(1024) void ygredbias_kernel(const float* __restrict__ part,
                                                         const float* __restrict__ Wg,
                                                         const float* __restrict__ Ug,
                                                         float* __restrict__ biasP,
                                                         float* __restrict__ biasD) {
    __shared__ float red[8][128];
    __shared__ float ygs[128];
    int bc = blockIdx.x;
    int t = threadIdx.x;
    int o = t & 127, g = t >> 7;
    float s = 0.f;
    for (int seg = g * 32; seg < g * 32 + 32; ++seg)
        s += part[((long)bc * 256 + seg) * 128 + o];
    red[g][o] = s;
    __syncthreads();
    if (t < 128) {
        float r = 0.f;
#pragma unroll
        for (int k = 0; k < 8; ++k) r += red[k][t];
        ygs[t] = r * (1.0f / 4096.0f);
    }
    __syncthreads();
    if (t < 256) {
        int oo = t & 127; bool isD = t >= 128;
        const float* row = (isD ? Ug : Wg) + oo * 256 + 128;
        float s2 = 0.f;
        for (int i = 0; i < 128; ++i) s2 = fmaf(row[i], ygs[i], s2);
        int b = bc / 3, c = bc % 3;
        (isD ? biasD : biasP)[((long)(b * 128 + oo)) * 3 + c] = s2;
    }
}

// ---------------- mean over N per (b, o, c) row of fp32 out1 ----------------
__global__ __launch_bounds__(256) void reduce_mean_kernel(const float* __restrict__ src, long bs,
                                                          float* __restrict__ dst, int N) {
    __shared__ float red[256];
    int row = blockIdx.x;
    int b = row / 384; int rr = row % 384;
    const float* p = src + (long)b * bs + (long)rr * N;
    float s = 0.f;
    for (int i = threadIdx.x; i < N; i += 256) s += p[i];
    red[threadIdx.x] = s;
    __syncthreads();
    for (int st = 128; st > 0; st >>= 1) {
        if (threadIdx.x < st) red[threadIdx.x] += red[threadIdx.x + st];
        __syncthreads();
    }
    if (threadIdx.x == 0) dst[row] = red[0] / (float)N;
}

extern "C" void kernel_launch(void* const* d_in, const int* in_sizes, int n_in,
                              void* d_out, int out_size, void* d_ws, size_t ws_size,
                              hipStream_t stream) {
    const float* x    = (const float*)d_in[0];
    const float* Win  = (const float*)d_in[1];
    const float* Uin  = (const float*)d_in[2];
    const float* Wl   = (const float*)d_in[3];
    const float* Ul   = (const float*)d_in[4];
    const float* Wg   = (const float*)d_in[5];
    const float* Ug   = (const float*)d_in[6];
    const float* Wout = (const float*)d_in[7];

    const int B = 2, N = 4096, H = 128;
    float* out0 = (float*)d_out;                 // (B,128,3) mean
    float* out1 = out0 + (long)B * H * 3;        // (B,128,3,N) fp32

    float* ws = (float*)d_ws;
    long off = 0;
    float4* pts4 = (float4*)ws;                  off += (long)B * N * 4;
    int* idx = (int*)(ws + off);                 off += (long)B * N * 16;
    const long ACT = (long)B * 3 * N * H;        // ushort count
    unsigned short* f0h = (unsigned short*)(ws + off);  off += ACT / 2;
    unsigned short* f0l = (unsigned short*)(ws + off);  off += ACT / 2;
    unsigned short* y1h = (unsigned short*)(ws + off);  off += ACT / 2;
    unsigned short* y1l = (unsigned short*)(ws + off);  off += ACT / 2;
    unsigned short* Aph = (unsigned short*)(ws + off);  off += 327680 / 2;
    unsigned short* Apl = (unsigned short*)(ws + off);  off += 327680 / 2;
    float* part  = ws + off;                     off += 6L * 256 * 128;
    float* biasP = ws + off;                     off += B * H * 3;
    float* biasD = ws + off;                     off += B * H * 3;
    // ~27.6 MB of workspace

    long bs128 = (long)H * 3 * N;

    setup_kernel<<<1280, 256, 0, stream>>>(x, pts4, Wl, Ul, Wg, Ug, Wout, Aph, Apl, N, B);
    knn_kernel<<<B * (N / 16), 1024, 0, stream>>>(pts4, idx, N);
    edge_kernel<<<B * (N / 8), 256, 0, stream>>>(pts4, idx, Win, Uin, f0h, f0l, N);

    // layer-0 input GEMM: y1 = LNA(Wl0 f0, Ul0 f0) + yg partials
    gemm0_kernel<<<256, 512, 0, stream>>>(Aph, Apl, 0L, f0h, f0l, y1h, y1l, part);

    for (int l = 0; l < 4; ++l) {
        ygredbias_kernel<<<6, 1024, 0, stream>>>(part,
            Wg + (long)l * H * 256, Ug + (long)l * H * 256, biasP, biasD);
        long aG = (long)(4 + l) * 32768;
        long aO = 262144 + (long)l * 16384;
        if (l < 3) {
            fused_kernel<true><<<256, 512, 0, stream>>>(
                Aph, Apl, aG, aO, (long)(l + 1) * 32768,
                y1h, y1l, biasP, biasD, out1, part, l > 0 ? 1 : 0);
        } else {
            fused_kernel<false><<<256, 512, 0, stream>>>(
                Aph, Apl, aG, aO, 0L,
                y1h, y1l, biasP, biasD, out1, part, 1);
        }
    }
    reduce_mean_kernel<<<B * H * 3, 256, 0, stream>>>(out1, bs128, out0, N);
}

// Round 13
// 254.241 us; speedup vs baseline: 1.3859x; 1.0860x over previous
//
#include <hip/hip_runtime.h>
#include <hip/hip_bf16.h>
#include <cfloat>

// VecPointNet on MI355X, round 13:
//  - Base = r12 (276.1us, best). Single change: kNN chunk-0 warm-up replaced by
//    a 64-lane bitonic sort on the exact double key u*4096+idx (ascending
//    double order == lex (d2,idx) == jax.lax.top_k tie semantics). Removes the
//    64-insert serial chain that was ~45% of all inserts; lanes 0..15 come out
//    holding the sorted top-16, and the unmodified r12 insert loop continues
//    from chunk 1 with a true (not stale-infinite) threshold.

typedef __attribute__((ext_vector_type(8))) short short8;
typedef __attribute__((ext_vector_type(4))) float f32x4;

__device__ __forceinline__ unsigned short f2bf(float f) {
    union { float f; unsigned u; } v; v.f = f;
    unsigned r = v.u + 0x7fffu + ((v.u >> 16) & 1u);
    return (unsigned short)(r >> 16);
}
__device__ __forceinline__ float bf2f(unsigned short h) {
    union { unsigned u; float f; } v; v.u = ((unsigned)h) << 16;
    return v.f;
}

// ---------------- setup: prep (pts4) + weight pack ----------------
__global__ __launch_bounds__(256) void setup_kernel(const float* __restrict__ x,
                                                    float4* __restrict__ pts4,
                                                    const float* __restrict__ Wl,
                                                    const float* __restrict__ Ul,
                                                    const float* __restrict__ Wg,
                                                    const float* __restrict__ Ug,
                                                    const float* __restrict__ Wout,
                                                    unsigned short* __restrict__ Ah,
                                                    unsigned short* __restrict__ Al,
                                                    int N, int B) {
    int t = blockIdx.x * 256 + threadIdx.x;     // 0..327679
    if (t < B * N) {
        int b = t / N, n = t - b * N;
        const float* xb = x + (long)b * 3 * N;
        float px = xb[n], py = xb[N + n], pz = xb[2 * N + n];
        pts4[t] = make_float4(px, py, pz, px * px + py * py + pz * pz);
    }
    int g, r, M; long base;
    if (t < 262144) { g = t >> 15; r = t & 32767; M = 256; base = (long)g << 15; }
    else { int t2 = t - 262144; g = 8 + (t2 >> 14); r = t2 & 16383; M = 128;
           base = 262144 + (long)(g - 8) * 16384; }
    int MF = M >> 4;
    int ks = r / (MF * 512);
    int mf = (r >> 9) % MF;
    int lane = (r >> 3) & 63;
    int j = r & 7;
    int m = mf * 16 + (lane & 15);
    int k = ks * 32 + ((lane >> 4) << 3) + j;
    const float* src; int ldw; int row;
    if (g < 4) {
        ldw = 128; row = m & 127;
        src = (m < 128) ? (Wl + (long)g * 128 * 128) : (Ul + (long)g * 128 * 128);
    } else if (g < 8) {
        ldw = 256; row = m & 127;
        int l = g - 4;
        src = (m < 128) ? (Wg + (long)l * 128 * 256) : (Ug + (long)l * 128 * 256);
    } else {
        ldw = 512; row = m;
        src = Wout + (g - 8) * 128;
    }
    float v = src[(long)row * ldw + k];
    unsigned short h = f2bf(v);
    Ah[base + r] = h;
    Al[base + r] = f2bf(v - bf2f(h));
}

// ---------------- knn: wave/query; bitonic-init chunk 0, stale-T DPP inserts after ----------------
__global__ __launch_bounds__(1024) void knn_kernel(const float4* __restrict__ pts4,
                                                   int* __restrict__ idxOut, int N) {
    __shared__ float4 cbuf[4096];   // 64 KB
    int t = threadIdx.x;
    int tilesPerB = N / 16;
    int b = blockIdx.x / tilesPerB;
    int q = (blockIdx.x % tilesPerB) * 16 + (t >> 6);
    int lane = t & 63;

    for (int i = t; i < N; i += 1024) cbuf[i] = pts4[b * N + i];
    __syncthreads();

    float4 Q = cbuf[q];
    unsigned ku; int ki;                         // lanes 0..15: sorted top-16 list

    // ---- chunk 0: 64-lane bitonic sort on exact key = u*4096 + idx ----
    {
        float4 C = cbuf[lane];
        float dot = Q.x * C.x + Q.y * C.y + Q.z * C.z;
        float d2 = Q.w + C.w - 2.0f * dot;        // same formula as reference
        unsigned u = __float_as_uint(d2);
        u ^= (unsigned)((int)u >> 31) | 0x80000000u;
        double key = (double)u * 4096.0 + (double)lane;
#pragma unroll
        for (int k = 2; k <= 64; k <<= 1) {
#pragma unroll
            for (int j = k >> 1; j > 0; j >>= 1) {
                double other = __shfl_xor(key, j);
                bool takeMin = (((lane & j) == 0) == ((lane & k) == 0));
                double mn = fmin(key, other), mx = fmax(key, other);
                key = takeMin ? mn : mx;
            }
        }
        long long kl = (long long)key;            // exact (key < 2^44)
        ki = (int)(kl & 4095);
        ku = (unsigned)(kl >> 12);
    }
    unsigned Tu = (unsigned)__builtin_amdgcn_readlane((int)ku, 15);

    for (int c0 = 64; c0 < N; c0 += 64) {
        float4 C = cbuf[c0 + lane];
        float dot = Q.x * C.x + Q.y * C.y + Q.z * C.z;
        float d2 = Q.w + C.w - 2.0f * dot;        // same formula as reference
        unsigned u = __float_as_uint(d2);
        u ^= (unsigned)((int)u >> 31) | 0x80000000u;
        int ci = c0 + lane;
        unsigned long long mask = __ballot(u <= Tu);
        while (mask) {
            int src = __ffsll(mask) - 1;
            mask &= mask - 1;
            unsigned vu = (unsigned)__builtin_amdgcn_readlane((int)u, src);
            int      vi = __builtin_amdgcn_readlane(ci, src);
            // k[lane-1] via DPP row_shr:1 (lanes 0..15 are one DPP row)
            unsigned kum1 = (unsigned)__builtin_amdgcn_update_dpp(
                                (int)ku, (int)ku, 0x111, 0xF, 0xF, false);
            int      kim1 = __builtin_amdgcn_update_dpp(
                                ki, ki, 0x111, 0xF, 0xF, false);
            if (lane == 0) { kum1 = 0u; kim1 = (-2147483647 - 1); }
            bool lem1 = (vu < kum1) || (vu == kum1 && vi < kim1);  // v < k[j-1]
            bool ltj  = (vu < ku)   || (vu == ku   && vi < ki);    // v < k[j]
            unsigned knu = lem1 ? kum1 : (ltj ? vu : ku);
            int      kni = lem1 ? kim1 : (ltj ? vi : ki);
            if (lane < 16) { ku = knu; ki = kni; }
        }
        Tu = (unsigned)__builtin_amdgcn_readlane((int)ku, 15);
    }
    if (lane < 16) idxOut[(b * N + q) * 16 + lane] = ki;
}

// ---------------- edge features + input LNA + mean over K -> f0 bf16 hi/lo ----------------
__global__ __launch_bounds__(256) void edge_kernel(const float4* __restrict__ pts4,
                                                   const int* __restrict__ idx,
                                                   const float* __restrict__ Win,
                                                   const float* __restrict__ Uin,
                                                   unsigned short* __restrict__ Yh,
                                                   unsigned short* __restrict__ Yl,
                                                   int N) {
    __shared__ float4 nbuf[8][16];
    __shared__ float4 cpt[8];
    int nTiles = N / 8;
    int b = blockIdx.x / nTiles;
    int n0 = (blockIdx.x % nTiles) * 8;
    int t = threadIdx.x;
    if (t < 128) {
        int pl = t >> 4, k = t & 15;
        int nb = idx[(b * N + n0 + pl) * 16 + k];
        nbuf[pl][k] = pts4[b * N + nb];
    } else if (t < 136) {
        cpt[t - 128] = pts4[b * N + n0 + (t - 128)];
    }
    __syncthreads();
    int o = t & 127, h = t >> 7;
    float w0 = Win[o * 3], w1 = Win[o * 3 + 1], w2 = Win[o * 3 + 2];
    float u0 = Uin[o * 3], u1 = Uin[o * 3 + 1], u2 = Uin[o * 3 + 2];
    for (int pl = h * 4; pl < h * 4 + 4; ++pl) {
        float4 c4 = cpt[pl];
        float inv = 1.0f / fmaxf(sqrtf(c4.w), 1e-12f);
        float ax = c4.x * inv, ay = c4.y * inv, az = c4.z * inv;
        float a0 = 0.f, a1 = 0.f, a2 = 0.f;
        for (int k = 0; k < 16; ++k) {
            float4 nb = nbuf[pl][k];
            float cr0 = ay * nb.z - az * nb.y;
            float cr1 = az * nb.x - ax * nb.z;
            float cr2 = ax * nb.y - ay * nb.x;
            float df0 = nb.x - c4.x, df1 = nb.y - c4.y, df2 = nb.z - c4.z;
            float P0 = w0 * cr0 + w1 * df0 + w2 * c4.x;
            float P1 = w0 * cr1 + w1 * df1 + w2 * c4.y;
            float P2 = w0 * cr2 + w1 * df2 + w2 * c4.z;
            float D0 = u0 * cr0 + u1 * df0 + u2 * c4.x;
            float D1 = u0 * cr1 + u1 * df1 + u2 * c4.y;
            float D2 = u0 * cr2 + u1 * df2 + u2 * c4.z;
            float dot = P0 * D0 + P1 * D1 + P2 * D2;
            float dsq = D0 * D0 + D1 * D1 + D2 * D2;
            if (dot < 0.0f) {
                float s = dot / (dsq + 1e-6f);
                P0 -= s * D0; P1 -= s * D1; P2 -= s * D2;
            }
            a0 += P0; a1 += P1; a2 += P2;
        }
        float vals[3] = { a0 * (1.0f / 16.0f), a1 * (1.0f / 16.0f), a2 * (1.0f / 16.0f) };
        long n = n0 + pl;
#pragma unroll
        for (int c = 0; c < 3; ++c) {
            long off = ((long)(b * 3 + c) * 4096 + n) * 128 + o;
            unsigned short hh = f2bf(vals[c]);
            Yh[off] = hh;
            Yl[off] = f2bf(vals[c] - bf2f(hh));
        }
    }
}

// ---------------- gemm0: y1 = LNA(Wl0 f0, Ul0 f0) + yg partials ----------------
__global__ __launch_bounds__(512, 1) void gemm0_kernel(
    const unsigned short* __restrict__ Aph, const unsigned short* __restrict__ Apl,
    long aOff,
    const unsigned short* __restrict__ Bh, const unsigned short* __restrict__ Bl,
    unsigned short* __restrict__ Oh, unsigned short* __restrict__ Ol,
    float* __restrict__ part)
{
    const int N = 4096;
    int t = threadIdx.x;
    int lane = t & 63, w = t >> 6;
    int mg = w >> 1, ng = w & 1;
    int b = blockIdx.x >> 7;
    int tile = blockIdx.x & 127;
    int ncol = tile * 32 + ng * 16 + (lane & 15);
    int kq = (lane >> 4) << 3;

    f32x4 accP[2][3] = {};
    f32x4 accD[2][3] = {};
    const unsigned short* AhB = Aph + aOff;
    const unsigned short* AlB = Apl + aOff;

#pragma unroll
    for (int ks = 0; ks < 4; ++ks) {
        short8 bh[3], bl[3];
#pragma unroll
        for (int c = 0; c < 3; ++c) {
            long boff = ((long)(b * 3 + c) * N + ncol) * 128 + ks * 32 + kq;
            bh[c] = *(const short8*)(Bh + boff);
            bl[c] = *(const short8*)(Bl + boff);
        }
#pragma unroll
        for (int pi = 0; pi < 2; ++pi) {
            int mf = 2 * mg + pi;
            long aoffP = (((long)ks * 16 + mf) * 64 + lane) * 8;
            short8 ahP = *(const short8*)(AhB + aoffP);
            short8 alP = *(const short8*)(AlB + aoffP);
#pragma unroll
            for (int c = 0; c < 3; ++c) {
                accP[pi][c] = __builtin_amdgcn_mfma_f32_16x16x32_bf16(ahP, bh[c], accP[pi][c], 0, 0, 0);
                accP[pi][c] = __builtin_amdgcn_mfma_f32_16x16x32_bf16(ahP, bl[c], accP[pi][c], 0, 0, 0);
                accP[pi][c] = __builtin_amdgcn_mfma_f32_16x16x32_bf16(alP, bh[c], accP[pi][c], 0, 0, 0);
            }
            long aoffD = (((long)ks * 16 + (8 + mf)) * 64 + lane) * 8;
            short8 ahD = *(const short8*)(AhB + aoffD);
            short8 alD = *(const short8*)(AlB + aoffD);
#pragma unroll
            for (int c = 0; c < 3; ++c) {
                accD[pi][c] = __builtin_amdgcn_mfma_f32_16x16x32_bf16(ahD, bh[c], accD[pi][c], 0, 0, 0);
                accD[pi][c] = __builtin_amdgcn_mfma_f32_16x16x32_bf16(ahD, bl[c], accD[pi][c], 0, 0, 0);
                accD[pi][c] = __builtin_amdgcn_mfma_f32_16x16x32_bf16(alD, bh[c], accD[pi][c], 0, 0, 0);
            }
        }
    }

#pragma unroll
    for (int pi = 0; pi < 2; ++pi) {
        int obase = 32 * mg + 16 * pi + ((lane >> 4) << 2);
        float Pv[3][4];
#pragma unroll
        for (int r = 0; r < 4; ++r) {
            float P[3], D[3];
#pragma unroll
            for (int c = 0; c < 3; ++c) { P[c] = accP[pi][c][r]; D[c] = accD[pi][c][r]; }
            float dot = P[0] * D[0] + P[1] * D[1] + P[2] * D[2];
            float dsq = D[0] * D[0] + D[1] * D[1] + D[2] * D[2];
            if (dot < 0.0f) {
                float s = dot / (dsq + 1e-6f);
                P[0] -= s * D[0]; P[1] -= s * D[1]; P[2] -= s * D[2];
            }
            Pv[0][r] = P[0]; Pv[1][r] = P[1]; Pv[2][r] = P[2];
        }
#pragma unroll
        for (int c = 0; c < 3; ++c) {
            unsigned short hs[4], ls[4];
#pragma unroll
            for (int r = 0; r < 4; ++r) {
                hs[r] = f2bf(Pv[c][r]);
                ls[r] = f2bf(Pv[c][r] - bf2f(hs[r]));
            }
            long ooff = ((long)(b * 3 + c) * N + ncol) * 128 + obase;
            *(ushort4*)(Oh + ooff) = make_ushort4(hs[0], hs[1], hs[2], hs[3]);
            *(ushort4*)(Ol + ooff) = make_ushort4(ls[0], ls[1], ls[2], ls[3]);
        }
#pragma unroll
        for (int c = 0; c < 3; ++c) {
#pragma unroll
            for (int r = 0; r < 4; ++r) {
                float v = Pv[c][r];
                v += __shfl_xor(v, 1);
                v += __shfl_xor(v, 2);
                v += __shfl_xor(v, 4);
                v += __shfl_xor(v, 8);
                if ((lane & 15) == 0)
                    part[((long)(b * 3 + c) * 256 + tile * 2 + ng) * 128 + (obase + r)] = v;
            }
        }
    }
}

// ---------------- fused: y2 = LNA(Wg y1+bP, Ug y1+bD) [LDS] -> Wout -> out1;
//                  if HASNEXT: y1' = LNA(Wl' y2, Ul' y2) -> y1 + yg partials ----------------
template<bool HASNEXT>
__global__ __launch_bounds__(512, 1) void fused_kernel(
    const unsigned short* __restrict__ Aph, const unsigned short* __restrict__ Apl,
    long aOffG, long aOffOut, long aOffNext,
    unsigned short* __restrict__ y1h, unsigned short* __restrict__ y1l,
    const float* __restrict__ biasP, const float* __restrict__ biasD,
    float* __restrict__ Ofp, float* __restrict__ part, int accum)
{
    const int N = 4096;
    __shared__ unsigned short ylds[2][3][2][2048];   // 48 KB
    int t = threadIdx.x;
    int lane = t & 63, w = t >> 6;
    int mg = w >> 1, ng = w & 1;
    int b = blockIdx.x >> 7;
    int tile = blockIdx.x & 127;
    int ncol = tile * 32 + ng * 16 + (lane & 15);
    int kq = (lane >> 4) << 3;

    // ---------- phase 1: y2 = LNA(Wg y1 + biasP, Ug y1 + biasD) -> ylds ----------
    {
        f32x4 accP[2][3] = {};
        f32x4 accD[2][3] = {};
        const unsigned short* AhB = Aph + aOffG;
        const unsigned short* AlB = Apl + aOffG;
#pragma unroll
        for (int ks = 0; ks < 4; ++ks) {
            short8 bh[3], bl[3];
#pragma unroll
            for (int c = 0; c < 3; ++c) {
                long boff = ((long)(b * 3 + c) * N + ncol) * 128 + ks * 32 + kq;
                bh[c] = *(const short8*)(y1h + boff);
                bl[c] = *(const short8*)(y1l + boff);
            }
#pragma unroll
            for (int pi = 0; pi < 2; ++pi) {
                int mf = 2 * mg + pi;
                long aoffP = (((long)ks * 16 + mf) * 64 + lane) * 8;
                short8 ahP = *(const short8*)(AhB + aoffP);
                short8 alP = *(const short8*)(AlB + aoffP);
#pragma unroll
                for (int c = 0; c < 3; ++c) {
                    accP[pi][c] = __builtin_amdgcn_mfma_f32_16x16x32_bf16(ahP, bh[c], accP[pi][c], 0, 0, 0);
                    accP[pi][c] = __builtin_amdgcn_mfma_f32_16x16x32_bf16(ahP, bl[c], accP[pi][c], 0, 0, 0);
                    accP[pi][c] = __builtin_amdgcn_mfma_f32_16x16x32_bf16(alP, bh[c], accP[pi][c], 0, 0, 0);
                }
                long aoffD = (((long)ks * 16 + (8 + mf)) * 64 + lane) * 8;
                short8 ahD = *(const short8*)(AhB + aoffD);
                short8 alD = *(const short8*)(AlB + aoffD);
#pragma unroll
                for (int c = 0; c < 3; ++c) {
                    accD[pi][c] = __builtin_amdgcn_mfma_f32_16x16x32_bf16(ahD, bh[c], accD[pi][c], 0, 0, 0);
                    accD[pi][c] = __builtin_amdgcn_mfma_f32_16x16x32_bf16(ahD, bl[c], accD[pi][c], 0, 0, 0);
                    accD[pi][c] = __builtin_amdgcn_mfma_f32_16x16x32_bf16(alD, bh[c], accD[pi][c], 0, 0, 0);
                }
            }
        }
#pragma unroll
        for (int pi = 0; pi < 2; ++pi) {
            int obase = 32 * mg + 16 * pi + ((lane >> 4) << 2);
            float Pv[3][4];
#pragma unroll
            for (int r = 0; r < 4; ++r) {
                int o = obase + r;
                float P[3], D[3];
#pragma unroll
                for (int c = 0; c < 3; ++c) {
                    long bb = ((long)(b * 128 + o)) * 3 + c;
                    P[c] = accP[pi][c][r] + biasP[bb];
                    D[c] = accD[pi][c][r] + biasD[bb];
                }
                float dot = P[0] * D[0] + P[1] * D[1] + P[2] * D[2];
                float dsq = D[0] * D[0] + D[1] * D[1] + D[2] * D[2];
                if (dot < 0.0f) {
                    float s = dot / (dsq + 1e-6f);
                    P[0] -= s * D[0]; P[1] -= s * D[1]; P[2] -= s * D[2];
                }
                Pv[0][r] = P[0]; Pv[1][r] = P[1]; Pv[2][r] = P[2];
            }
#pragma unroll
            for (int c = 0; c < 3; ++c) {
                unsigned short hs[4], ls[4];
#pragma unroll
                for (int r = 0; r < 4; ++r) {
                    hs[r] = f2bf(Pv[c][r]);
                    ls[r] = f2bf(Pv[c][r] - bf2f(hs[r]));
                }
                int li = ((obase >> 3) << 7) + ((lane & 15) << 3) + (obase & 7);
                *(ushort4*)&ylds[ng][c][0][li] = make_ushort4(hs[0], hs[1], hs[2], hs[3]);
                *(ushort4*)&ylds[ng][c][1][li] = make_ushort4(ls[0], ls[1], ls[2], ls[3]);
            }
        }
    }
    __syncthreads();

    // ---------- phase 2: out1 (+)= Wout_l @ y2 ----------
    {
        f32x4 accO[2][3] = {};
        const unsigned short* AoH = Aph + aOffOut;
        const unsigned short* AoL = Apl + aOffOut;
#pragma unroll
        for (int ks = 0; ks < 4; ++ks) {
            short8 yh[3], yl[3];
            int li = (((ks << 2) + (lane >> 4)) << 7) + ((lane & 15) << 3);
#pragma unroll
            for (int c = 0; c < 3; ++c) {
                yh[c] = *(const short8*)&ylds[ng][c][0][li];
                yl[c] = *(const short8*)&ylds[ng][c][1][li];
            }
#pragma unroll
            for (int pi = 0; pi < 2; ++pi) {
                int mf = 2 * mg + pi;
                long aoff = (((long)ks * 8 + mf) * 64 + lane) * 8;
                short8 ah = *(const short8*)(AoH + aoff);
                short8 al = *(const short8*)(AoL + aoff);
#pragma unroll
                for (int c = 0; c < 3; ++c) {
                    accO[pi][c] = __builtin_amdgcn_mfma_f32_16x16x32_bf16(ah, yh[c], accO[pi][c], 0, 0, 0);
                    accO[pi][c] = __builtin_amdgcn_mfma_f32_16x16x32_bf16(ah, yl[c], accO[pi][c], 0, 0, 0);
                    accO[pi][c] = __builtin_amdgcn_mfma_f32_16x16x32_bf16(al, yh[c], accO[pi][c], 0, 0, 0);
                }
            }
        }
#pragma unroll
        for (int pi = 0; pi < 2; ++pi) {
            int obase = 32 * mg + 16 * pi + ((lane >> 4) << 2);
#pragma unroll
            for (int r = 0; r < 4; ++r) {
                int o = obase + r;
#pragma unroll
                for (int c = 0; c < 3; ++c) {
                    long off = ((long)(b * 128 + o) * 3 + c) * N + ncol;
                    float v = accO[pi][c][r];
                    if (accum) v += Ofp[off];
                    Ofp[off] = v;
                }
            }
        }
    }

    // ---------- phase 3 (HASNEXT): y1' = LNA(Wl' y2, Ul' y2) -> y1 + yg partials ----------
    if (HASNEXT) {
        f32x4 accP[2][3] = {};
        f32x4 accD[2][3] = {};
        const unsigned short* AnH = Aph + aOffNext;
        const unsigned short* AnL = Apl + aOffNext;
#pragma unroll
        for (int ks = 0; ks < 4; ++ks) {
            short8 bh[3], bl[3];
            int li = (((ks << 2) + (lane >> 4)) << 7) + ((lane & 15) << 3);
#pragma unroll
            for (int c = 0; c < 3; ++c) {
                bh[c] = *(const short8*)&ylds[ng][c][0][li];
                bl[c] = *(const short8*)&ylds[ng][c][1][li];
            }
#pragma unroll
            for (int pi = 0; pi < 2; ++pi) {
                int mf = 2 * mg + pi;
                long aoffP = (((long)ks * 16 + mf) * 64 + lane) * 8;
                short8 ahP = *(const short8*)(AnH + aoffP);
                short8 alP = *(const short8*)(AnL + aoffP);
#pragma unroll
                for (int c = 0; c < 3; ++c) {
                    accP[pi][c] = __builtin_amdgcn_mfma_f32_16x16x32_bf16(ahP, bh[c], accP[pi][c], 0, 0, 0);
                    accP[pi][c] = __builtin_amdgcn_mfma_f32_16x16x32_bf16(ahP, bl[c], accP[pi][c], 0, 0, 0);
                    accP[pi][c] = __builtin_amdgcn_mfma_f32_16x16x32_bf16(alP, bh[c], accP[pi][c], 0, 0, 0);
                }
                long aoffD = (((long)ks * 16 + (8 + mf)) * 64 + lane) * 8;
                short8 ahD = *(const short8*)(AnH + aoffD);
                short8 alD = *(const short8*)(AnL + aoffD);
#pragma unroll
                for (int c = 0; c < 3; ++c) {
                    accD[pi][c] = __builtin_amdgcn_mfma_f32_16x16x32_bf16(ahD, bh[c], accD[pi][c], 0, 0, 0);
                    accD[pi][c] = __builtin_amdgcn_mfma_f32_16x16x32_bf16(ahD, bl[c], accD[pi][c], 0, 0, 0);
                    accD[pi][c] = __builtin_amdgcn_mfma_f32_16x16x32_bf16(alD, bh[c], accD[pi][c], 0, 0, 0);
                }
            }
        }
#pragma unroll
        for (int pi = 0; pi < 2; ++pi) {
            int obase = 32 * mg + 16 * pi + ((lane >> 4) << 2);
            float Pv[3][4];
#pragma unroll
            for (int r = 0; r < 4; ++r) {
                float P[3], D[3];
#pragma unroll
                for (int c = 0; c < 3; ++c) { P[c] = accP[pi][c][r]; D[c] = accD[pi][c][r]; }
                float dot = P[0] * D[0] + P[1] * D[1] + P[2] * D[2];
                float dsq = D[0] * D[0] + D[1] * D[1] + D[2] * D[2];
                if (dot < 0.0f) {
                    float s = dot / (dsq + 1e-6f);
                    P[0] -= s * D[0]; P[1] -= s * D[1]; P[2] -= s * D[2];
                }
                Pv[0][r] = P[0]; Pv[1][r] = P[1]; Pv[2][r] = P[2];
            }
#pragma unroll
            for (int c = 0; c < 3; ++c) {
                unsigned short hs[4], ls[4];
#pragma unroll
                for (int r = 0; r < 4; ++r) {
                    hs[r] = f2bf(Pv[c][r]);
                    ls[r] = f2bf(Pv[c][r] - bf2f(hs[r]));
                }
                long ooff = ((long)(b * 3 + c) * N + ncol) * 128 + obase;
                *(ushort4*)(y1h + ooff) = make_ushort4(hs[0], hs[1], hs[2], hs[3]);
                *(ushort4*)(y1l + ooff) = make_ushort4(ls[0], ls[1], ls[2], ls[3]);
            }
#pragma unroll
            for (int c = 0; c < 3; ++c) {
#pragma unroll
                for (int r = 0; r < 4; ++r) {
                    float v = Pv[c][r];
                    v += __shfl_xor(v, 1);
                    v += __shfl_xor(v, 2);
                    v += __shfl_xor(v, 4);
                    v += __shfl_xor(v, 8);
                    if ((lane & 15) == 0)
                        part[((long)(b * 3 + c) * 256 + tile * 2 + ng) * 128 + (obase + r)] = v;
                }
            }
        }
    }
}

// ---------------- fused yg reduce + bias: 6 blocks (b*3+c), 1024 threads ----------------
__global__ __launch_bounds__(1024) void ygredbias_kernel(const float* __restrict__ part,
                                                         const float* __restrict__ Wg,
                                                         const float* __restrict__ Ug,
                                                         float* __restrict__ biasP,
                                                         float* __restrict__ biasD) {
    __shared__ float red[8][128];
    __shared__ float ygs[128];
    int bc = blockIdx.x;
    int t = threadIdx.x;
    int o = t & 127, g = t >> 7;
    float s = 0.f;
    for (int seg = g * 32; seg < g * 32 + 32; ++seg)
        s += part[((long)bc * 256 + seg) * 128 + o];
    red[g][o] = s;
    __syncthreads();
    if (t < 128) {
        float r = 0.f;
#pragma unroll
        for (int k = 0; k < 8; ++k) r += red[k][t];
        ygs[t] = r * (1.0f / 4096.0f);
    }
    __syncthreads();
    if (t < 256) {
        int oo = t & 127; bool isD = t >= 128;
        const float* row = (isD ? Ug : Wg) + oo * 256 + 128;
        float s2 = 0.f;
        for (int i = 0; i < 128; ++i) s2 = fmaf(row[i], ygs[i], s2);
        int b = bc / 3, c = bc % 3;
        (isD ? biasD : biasP)[((long)(b * 128 + oo)) * 3 + c] = s2;
    }
}

// ---------------- mean over N per (b, o, c) row of fp32 out1 ----------------
__global__ __launch_bounds__(256) void reduce_mean_kernel(const float* __restrict__ src, long bs,
                                                          float* __restrict__ dst, int N) {
    __shared__ float red[256];
    int row = blockIdx.x;
    int b = row / 384; int rr = row % 384;
    const float* p = src + (long)b * bs + (long)rr * N;
    float s = 0.f;
    for (int i = threadIdx.x; i < N; i += 256) s += p[i];
    red[threadIdx.x] = s;
    __syncthreads();
    for (int st = 128; st > 0; st >>= 1) {
        if (threadIdx.x < st) red[threadIdx.x] += red[threadIdx.x + st];
        __syncthreads();
    }
    if (threadIdx.x == 0) dst[row] = red[0] / (float)N;
}

extern "C" void kernel_launch(void* const* d_in, const int* in_sizes, int n_in,
                              void* d_out, int out_size, void* d_ws, size_t ws_size,
                              hipStream_t stream) {
    const float* x    = (const float*)d_in[0];
    const float* Win  = (const float*)d_in[1];
    const float* Uin  = (const float*)d_in[2];
    const float* Wl   = (const float*)d_in[3];
    const float* Ul   = (const float*)d_in[4];
    const float* Wg   = (const float*)d_in[5];
    const float* Ug   = (const float*)d_in[6];
    const float* Wout = (const float*)d_in[7];

    const int B = 2, N = 4096, H = 128;
    float* out0 = (float*)d_out;                 // (B,128,3) mean
    float* out1 = out0 + (long)B * H * 3;        // (B,128,3,N) fp32

    float* ws = (float*)d_ws;
    long off = 0;
    float4* pts4 = (float4*)ws;                  off += (long)B * N * 4;
    int* idx = (int*)(ws + off);                 off += (long)B * N * 16;
    const long ACT = (long)B * 3 * N * H;        // ushort count
    unsigned short* f0h = (unsigned short*)(ws + off);  off += ACT / 2;
    unsigned short* f0l = (unsigned short*)(ws + off);  off += ACT / 2;
    unsigned short* y1h = (unsigned short*)(ws + off);  off += ACT / 2;
    unsigned short* y1l = (unsigned short*)(ws + off);  off += ACT / 2;
    unsigned short* Aph = (unsigned short*)(ws + off);  off += 327680 / 2;
    unsigned short* Apl = (unsigned short*)(ws + off);  off += 327680 / 2;
    float* part  = ws + off;                     off += 6L * 256 * 128;
    float* biasP = ws + off;                     off += B * H * 3;
    float* biasD = ws + off;                     off += B * H * 3;
    // ~27.6 MB of workspace

    long bs128 = (long)H * 3 * N;

    setup_kernel<<<1280, 256, 0, stream>>>(x, pts4, Wl, Ul, Wg, Ug, Wout, Aph, Apl, N, B);
    knn_kernel<<<B * (N / 16), 1024, 0, stream>>>(pts4, idx, N);
    edge_kernel<<<B * (N / 8), 256, 0, stream>>>(pts4, idx, Win, Uin, f0h, f0l, N);

    // layer-0 input GEMM: y1 = LNA(Wl0 f0, Ul0 f0) + yg partials
    gemm0_kernel<<<256, 512, 0, stream>>>(Aph, Apl, 0L, f0h, f0l, y1h, y1l, part);

    for (int l = 0; l < 4; ++l) {
        ygredbias_kernel<<<6, 1024, 0, stream>>>(part,
            Wg + (long)l * H * 256, Ug + (long)l * H * 256, biasP, biasD);
        long aG = (long)(4 + l) * 32768;
        long aO = 262144 + (long)l * 16384;
        if (l < 3) {
            fused_kernel<true><<<256, 512, 0, stream>>>(
                Aph, Apl, aG, aO, (long)(l + 1) * 32768,
                y1h, y1l, biasP, biasD, out1, part, l > 0 ? 1 : 0);
        } else {
            fused_kernel<false><<<256, 512, 0, stream>>>(
                Aph, Apl, aG, aO, 0L,
                y1h, y1l, biasP, biasD, out1, part, 1);
        }
    }
    reduce_mean_kernel<<<B * H * 3, 256, 0, stream>>>(out1, bs128, out0, N);
}

// Round 14
// 250.648 us; speedup vs baseline: 1.4057x; 1.0143x over previous
//
#include <hip/hip_runtime.h>
#include <hip/hip_bf16.h>
#include <cfloat>

// VecPointNet on MI355X, round 14:
//  - Base = r13 (254.2us, best). Two fusions using already-proven patterns:
//    (1) edge merged into gemm0: edge features for the block's 32 points go to
//        a 48KB LDS tile in the exact ylds fragment layout; gemm0 phase reads
//        B-fragments from LDS. Kills edge dispatch + f0 buffers + 25MB traffic.
//    (2) reduce_mean folded into fused<false>: out1 values already in regs ->
//        shfl_xor 16-col partials into `part` (dead by then); tiny 6-block
//        out0red finalizes. Kills the 768-block 12.6MB reduce_mean.
//  - knn unchanged (48us, near issue-bound floor).

typedef __attribute__((ext_vector_type(8))) short short8;
typedef __attribute__((ext_vector_type(4))) float f32x4;

__device__ __forceinline__ unsigned short f2bf(float f) {
    union { float f; unsigned u; } v; v.f = f;
    unsigned r = v.u + 0x7fffu + ((v.u >> 16) & 1u);
    return (unsigned short)(r >> 16);
}
__device__ __forceinline__ float bf2f(unsigned short h) {
    union { unsigned u; float f; } v; v.u = ((unsigned)h) << 16;
    return v.f;
}

// ---------------- setup: prep (pts4) + weight pack ----------------
__global__ __launch_bounds__(256) void setup_kernel(const float* __restrict__ x,
                                                    float4* __restrict__ pts4,
                                                    const float* __restrict__ Wl,
                                                    const float* __restrict__ Ul,
                                                    const float* __restrict__ Wg,
                                                    const float* __restrict__ Ug,
                                                    const float* __restrict__ Wout,
                                                    unsigned short* __restrict__ Ah,
                                                    unsigned short* __restrict__ Al,
                                                    int N, int B) {
    int t = blockIdx.x * 256 + threadIdx.x;     // 0..327679
    if (t < B * N) {
        int b = t / N, n = t - b * N;
        const float* xb = x + (long)b * 3 * N;
        float px = xb[n], py = xb[N + n], pz = xb[2 * N + n];
        pts4[t] = make_float4(px, py, pz, px * px + py * py + pz * pz);
    }
    int g, r, M; long base;
    if (t < 262144) { g = t >> 15; r = t & 32767; M = 256; base = (long)g << 15; }
    else { int t2 = t - 262144; g = 8 + (t2 >> 14); r = t2 & 16383; M = 128;
           base = 262144 + (long)(g - 8) * 16384; }
    int MF = M >> 4;
    int ks = r / (MF * 512);
    int mf = (r >> 9) % MF;
    int lane = (r >> 3) & 63;
    int j = r & 7;
    int m = mf * 16 + (lane & 15);
    int k = ks * 32 + ((lane >> 4) << 3) + j;
    const float* src; int ldw; int row;
    if (g < 4) {
        ldw = 128; row = m & 127;
        src = (m < 128) ? (Wl + (long)g * 128 * 128) : (Ul + (long)g * 128 * 128);
    } else if (g < 8) {
        ldw = 256; row = m & 127;
        int l = g - 4;
        src = (m < 128) ? (Wg + (long)l * 128 * 256) : (Ug + (long)l * 128 * 256);
    } else {
        ldw = 512; row = m;
        src = Wout + (g - 8) * 128;
    }
    float v = src[(long)row * ldw + k];
    unsigned short h = f2bf(v);
    Ah[base + r] = h;
    Al[base + r] = f2bf(v - bf2f(h));
}

// ---------------- knn (r13): bitonic-init chunk 0, stale-T DPP inserts ----------------
__global__ __launch_bounds__(1024) void knn_kernel(const float4* __restrict__ pts4,
                                                   int* __restrict__ idxOut, int N) {
    __shared__ float4 cbuf[4096];   // 64 KB
    int t = threadIdx.x;
    int tilesPerB = N / 16;
    int b = blockIdx.x / tilesPerB;
    int q = (blockIdx.x % tilesPerB) * 16 + (t >> 6);
    int lane = t & 63;

    for (int i = t; i < N; i += 1024) cbuf[i] = pts4[b * N + i];
    __syncthreads();

    float4 Q = cbuf[q];
    unsigned ku; int ki;                         // lanes 0..15: sorted top-16 list

    // ---- chunk 0: 64-lane bitonic sort on exact key = u*4096 + idx ----
    {
        float4 C = cbuf[lane];
        float dot = Q.x * C.x + Q.y * C.y + Q.z * C.z;
        float d2 = Q.w + C.w - 2.0f * dot;        // same formula as reference
        unsigned u = __float_as_uint(d2);
        u ^= (unsigned)((int)u >> 31) | 0x80000000u;
        double key = (double)u * 4096.0 + (double)lane;
#pragma unroll
        for (int k = 2; k <= 64; k <<= 1) {
#pragma unroll
            for (int j = k >> 1; j > 0; j >>= 1) {
                double other = __shfl_xor(key, j);
                bool takeMin = (((lane & j) == 0) == ((lane & k) == 0));
                double mn = fmin(key, other), mx = fmax(key, other);
                key = takeMin ? mn : mx;
            }
        }
        long long kl = (long long)key;            // exact (key < 2^44)
        ki = (int)(kl & 4095);
        ku = (unsigned)(kl >> 12);
    }
    unsigned Tu = (unsigned)__builtin_amdgcn_readlane((int)ku, 15);

    for (int c0 = 64; c0 < N; c0 += 64) {
        float4 C = cbuf[c0 + lane];
        float dot = Q.x * C.x + Q.y * C.y + Q.z * C.z;
        float d2 = Q.w + C.w - 2.0f * dot;        // same formula as reference
        unsigned u = __float_as_uint(d2);
        u ^= (unsigned)((int)u >> 31) | 0x80000000u;
        int ci = c0 + lane;
        unsigned long long mask = __ballot(u <= Tu);
        while (mask) {
            int src = __ffsll(mask) - 1;
            mask &= mask - 1;
            unsigned vu = (unsigned)__builtin_amdgcn_readlane((int)u, src);
            int      vi = __builtin_amdgcn_readlane(ci, src);
            unsigned kum1 = (unsigned)__builtin_amdgcn_update_dpp(
                                (int)ku, (int)ku, 0x111, 0xF, 0xF, false);
            int      kim1 = __builtin_amdgcn_update_dpp(
                                ki, ki, 0x111, 0xF, 0xF, false);
            if (lane == 0) { kum1 = 0u; kim1 = (-2147483647 - 1); }
            bool lem1 = (vu < kum1) || (vu == kum1 && vi < kim1);  // v < k[j-1]
            bool ltj  = (vu < ku)   || (vu == ku   && vi < ki);    // v < k[j]
            unsigned knu = lem1 ? kum1 : (ltj ? vu : ku);
            int      kni = lem1 ? kim1 : (ltj ? vi : ki);
            if (lane < 16) { ku = knu; ki = kni; }
        }
        Tu = (unsigned)__builtin_amdgcn_readlane((int)ku, 15);
    }
    if (lane < 16) idxOut[(b * N + q) * 16 + lane] = ki;
}

// ---------------- edge + gemm0 merged: edge features -> LDS f0 tile -> MFMA ----------------
// Grid 256 blocks (b*128 + tile32), 512 threads. Phase E: 32 points' edge
// features into flds (ylds fragment layout). Phase G: y1 = LNA(Wl0 f0, Ul0 f0)
// + yg partials, B-fragments read from flds.
__global__ __launch_bounds__(512, 1) void edgegemm0_kernel(
    const float4* __restrict__ pts4, const int* __restrict__ idx,
    const float* __restrict__ Win, const float* __restrict__ Uin,
    const unsigned short* __restrict__ Aph, const unsigned short* __restrict__ Apl,
    unsigned short* __restrict__ Oh, unsigned short* __restrict__ Ol,
    float* __restrict__ part, int N)
{
    __shared__ float4 nbuf[32][16];                 // 8 KB
    __shared__ float4 cpt[32];
    __shared__ unsigned short flds[2][3][2][2048];  // 48 KB, ylds layout
    int t = threadIdx.x;
    int lane = t & 63, w = t >> 6;
    int mg = w >> 1, ng = w & 1;
    int b = blockIdx.x >> 7;
    int tile = blockIdx.x & 127;
    int n0 = tile * 32;

    // ---- phase E: stage neighbors + compute edge features ----
    {
        int pl = t >> 4, k = t & 15;
        int nb = idx[(b * N + n0 + pl) * 16 + k];
        nbuf[pl][k] = pts4[b * N + nb];
        if (t < 32) cpt[t] = pts4[b * N + n0 + t];
    }
    __syncthreads();
    {
        int o = t & 127, grp = t >> 7;
        float w0 = Win[o * 3], w1 = Win[o * 3 + 1], w2 = Win[o * 3 + 2];
        float u0 = Uin[o * 3], u1 = Uin[o * 3 + 1], u2 = Uin[o * 3 + 2];
        for (int pl = grp * 8; pl < grp * 8 + 8; ++pl) {
            float4 c4 = cpt[pl];
            float inv = 1.0f / fmaxf(sqrtf(c4.w), 1e-12f);
            float ax = c4.x * inv, ay = c4.y * inv, az = c4.z * inv;
            float a0 = 0.f, a1 = 0.f, a2 = 0.f;
            for (int k = 0; k < 16; ++k) {
                float4 nb = nbuf[pl][k];
                float cr0 = ay * nb.z - az * nb.y;
                float cr1 = az * nb.x - ax * nb.z;
                float cr2 = ax * nb.y - ay * nb.x;
                float df0 = nb.x - c4.x, df1 = nb.y - c4.y, df2 = nb.z - c4.z;
                float P0 = w0 * cr0 + w1 * df0 + w2 * c4.x;
                float P1 = w0 * cr1 + w1 * df1 + w2 * c4.y;
                float P2 = w0 * cr2 + w1 * df2 + w2 * c4.z;
                float D0 = u0 * cr0 + u1 * df0 + u2 * c4.x;
                float D1 = u0 * cr1 + u1 * df1 + u2 * c4.y;
                float D2 = u0 * cr2 + u1 * df2 + u2 * c4.z;
                float dot = P0 * D0 + P1 * D1 + P2 * D2;
                float dsq = D0 * D0 + D1 * D1 + D2 * D2;
                if (dot < 0.0f) {
                    float s = dot / (dsq + 1e-6f);
                    P0 -= s * D0; P1 -= s * D1; P2 -= s * D2;
                }
                a0 += P0; a1 += P1; a2 += P2;
            }
            float vals[3] = { a0 * (1.0f / 16.0f), a1 * (1.0f / 16.0f), a2 * (1.0f / 16.0f) };
            int ngg = pl >> 4, col = pl & 15;
            int li = ((o >> 3) << 7) + (col << 3) + (o & 7);
#pragma unroll
            for (int c = 0; c < 3; ++c) {
                unsigned short hh = f2bf(vals[c]);
                flds[ngg][c][0][li] = hh;
                flds[ngg][c][1][li] = f2bf(vals[c] - bf2f(hh));
            }
        }
    }
    __syncthreads();

    // ---- phase G: y1 = LNA(Wl0 f0, Ul0 f0) + yg partials (B from flds) ----
    int ncol = tile * 32 + ng * 16 + (lane & 15);
    f32x4 accP[2][3] = {};
    f32x4 accD[2][3] = {};
#pragma unroll
    for (int ks = 0; ks < 4; ++ks) {
        short8 bh[3], bl[3];
        int li = (((ks << 2) + (lane >> 4)) << 7) + ((lane & 15) << 3);
#pragma unroll
        for (int c = 0; c < 3; ++c) {
            bh[c] = *(const short8*)&flds[ng][c][0][li];
            bl[c] = *(const short8*)&flds[ng][c][1][li];
        }
#pragma unroll
        for (int pi = 0; pi < 2; ++pi) {
            int mf = 2 * mg + pi;
            long aoffP = (((long)ks * 16 + mf) * 64 + lane) * 8;
            short8 ahP = *(const short8*)(Aph + aoffP);
            short8 alP = *(const short8*)(Apl + aoffP);
#pragma unroll
            for (int c = 0; c < 3; ++c) {
                accP[pi][c] = __builtin_amdgcn_mfma_f32_16x16x32_bf16(ahP, bh[c], accP[pi][c], 0, 0, 0);
                accP[pi][c] = __builtin_amdgcn_mfma_f32_16x16x32_bf16(ahP, bl[c], accP[pi][c], 0, 0, 0);
                accP[pi][c] = __builtin_amdgcn_mfma_f32_16x16x32_bf16(alP, bh[c], accP[pi][c], 0, 0, 0);
            }
            long aoffD = (((long)ks * 16 + (8 + mf)) * 64 + lane) * 8;
            short8 ahD = *(const short8*)(Aph + aoffD);
            short8 alD = *(const short8*)(Apl + aoffD);
#pragma unroll
            for (int c = 0; c < 3; ++c) {
                accD[pi][c] = __builtin_amdgcn_mfma_f32_16x16x32_bf16(ahD, bh[c], accD[pi][c], 0, 0, 0);
                accD[pi][c] = __builtin_amdgcn_mfma_f32_16x16x32_bf16(ahD, bl[c], accD[pi][c], 0, 0, 0);
                accD[pi][c] = __builtin_amdgcn_mfma_f32_16x16x32_bf16(alD, bh[c], accD[pi][c], 0, 0, 0);
            }
        }
    }

#pragma unroll
    for (int pi = 0; pi < 2; ++pi) {
        int obase = 32 * mg + 16 * pi + ((lane >> 4) << 2);
        float Pv[3][4];
#pragma unroll
        for (int r = 0; r < 4; ++r) {
            float P[3], D[3];
#pragma unroll
            for (int c = 0; c < 3; ++c) { P[c] = accP[pi][c][r]; D[c] = accD[pi][c][r]; }
            float dot = P[0] * D[0] + P[1] * D[1] + P[2] * D[2];
            float dsq = D[0] * D[0] + D[1] * D[1] + D[2] * D[2];
            if (dot < 0.0f) {
                float s = dot / (dsq + 1e-6f);
                P[0] -= s * D[0]; P[1] -= s * D[1]; P[2] -= s * D[2];
            }
            Pv[0][r] = P[0]; Pv[1][r] = P[1]; Pv[2][r] = P[2];
        }
#pragma unroll
        for (int c = 0; c < 3; ++c) {
            unsigned short hs[4], ls[4];
#pragma unroll
            for (int r = 0; r < 4; ++r) {
                hs[r] = f2bf(Pv[c][r]);
                ls[r] = f2bf(Pv[c][r] - bf2f(hs[r]));
            }
            long ooff = ((long)(b * 3 + c) * N + ncol) * 128 + obase;
            *(ushort4*)(Oh + ooff) = make_ushort4(hs[0], hs[1], hs[2], hs[3]);
            *(ushort4*)(Ol + ooff) = make_ushort4(ls[0], ls[1], ls[2], ls[3]);
        }
#pragma unroll
        for (int c = 0; c < 3; ++c) {
#pragma unroll
            for (int r = 0; r < 4; ++r) {
                float v = Pv[c][r];
                v += __shfl_xor(v, 1);
                v += __shfl_xor(v, 2);
                v += __shfl_xor(v, 4);
                v += __shfl_xor(v, 8);
                if ((lane & 15) == 0)
                    part[((long)(b * 3 + c) * 256 + tile * 2 + ng) * 128 + (obase + r)] = v;
            }
        }
    }
}

// ---------------- fused: y2 = LNA(Wg y1+bP, Ug y1+bD) [LDS] -> Wout -> out1;
//                  HASNEXT: y1' = LNA(Wl' y2, Ul' y2); else: out0 partials ----------------
template<bool HASNEXT>
__global__ __launch_bounds__(512, 1) void fused_kernel(
    const unsigned short* __restrict__ Aph, const unsigned short* __restrict__ Apl,
    long aOffG, long aOffOut, long aOffNext,
    unsigned short* __restrict__ y1h, unsigned short* __restrict__ y1l,
    const float* __restrict__ biasP, const float* __restrict__ biasD,
    float* __restrict__ Ofp, float* __restrict__ part, int accum)
{
    const int N = 4096;
    __shared__ unsigned short ylds[2][3][2][2048];   // 48 KB
    int t = threadIdx.x;
    int lane = t & 63, w = t >> 6;
    int mg = w >> 1, ng = w & 1;
    int b = blockIdx.x >> 7;
    int tile = blockIdx.x & 127;
    int ncol = tile * 32 + ng * 16 + (lane & 15);
    int kq = (lane >> 4) << 3;

    // ---------- phase 1: y2 = LNA(Wg y1 + biasP, Ug y1 + biasD) -> ylds ----------
    {
        f32x4 accP[2][3] = {};
        f32x4 accD[2][3] = {};
        const unsigned short* AhB = Aph + aOffG;
        const unsigned short* AlB = Apl + aOffG;
#pragma unroll
        for (int ks = 0; ks < 4; ++ks) {
            short8 bh[3], bl[3];
#pragma unroll
            for (int c = 0; c < 3; ++c) {
                long boff = ((long)(b * 3 + c) * N + ncol) * 128 + ks * 32 + kq;
                bh[c] = *(const short8*)(y1h + boff);
                bl[c] = *(const short8*)(y1l + boff);
            }
#pragma unroll
            for (int pi = 0; pi < 2; ++pi) {
                int mf = 2 * mg + pi;
                long aoffP = (((long)ks * 16 + mf) * 64 + lane) * 8;
                short8 ahP = *(const short8*)(AhB + aoffP);
                short8 alP = *(const short8*)(AlB + aoffP);
#pragma unroll
                for (int c = 0; c < 3; ++c) {
                    accP[pi][c] = __builtin_amdgcn_mfma_f32_16x16x32_bf16(ahP, bh[c], accP[pi][c], 0, 0, 0);
                    accP[pi][c] = __builtin_amdgcn_mfma_f32_16x16x32_bf16(ahP, bl[c], accP[pi][c], 0, 0, 0);
                    accP[pi][c] = __builtin_amdgcn_mfma_f32_16x16x32_bf16(alP, bh[c], accP[pi][c], 0, 0, 0);
                }
                long aoffD = (((long)ks * 16 + (8 + mf)) * 64 + lane) * 8;
                short8 ahD = *(const short8*)(AhB + aoffD);
                short8 alD = *(const short8*)(AlB + aoffD);
#pragma unroll
                for (int c = 0; c < 3; ++c) {
                    accD[pi][c] = __builtin_amdgcn_mfma_f32_16x16x32_bf16(ahD, bh[c], accD[pi][c], 0, 0, 0);
                    accD[pi][c] = __builtin_amdgcn_mfma_f32_16x16x32_bf16(ahD, bl[c], accD[pi][c], 0, 0, 0);
                    accD[pi][c] = __builtin_amdgcn_mfma_f32_16x16x32_bf16(alD, bh[c], accD[pi][c], 0, 0, 0);
                }
            }
        }
#pragma unroll
        for (int pi = 0; pi < 2; ++pi) {
            int obase = 32 * mg + 16 * pi + ((lane >> 4) << 2);
            float Pv[3][4];
#pragma unroll
            for (int r = 0; r < 4; ++r) {
                int o = obase + r;
                float P[3], D[3];
#pragma unroll
                for (int c = 0; c < 3; ++c) {
                    long bb = ((long)(b * 128 + o)) * 3 + c;
                    P[c] = accP[pi][c][r] + biasP[bb];
                    D[c] = accD[pi][c][r] + biasD[bb];
                }
                float dot = P[0] * D[0] + P[1] * D[1] + P[2] * D[2];
                float dsq = D[0] * D[0] + D[1] * D[1] + D[2] * D[2];
                if (dot < 0.0f) {
                    float s = dot / (dsq + 1e-6f);
                    P[0] -= s * D[0]; P[1] -= s * D[1]; P[2] -= s * D[2];
                }
                Pv[0][r] = P[0]; Pv[1][r] = P[1]; Pv[2][r] = P[2];
            }
#pragma unroll
            for (int c = 0; c < 3; ++c) {
                unsigned short hs[4], ls[4];
#pragma unroll
                for (int r = 0; r < 4; ++r) {
                    hs[r] = f2bf(Pv[c][r]);
                    ls[r] = f2bf(Pv[c][r] - bf2f(hs[r]));
                }
                int li = ((obase >> 3) << 7) + ((lane & 15) << 3) + (obase & 7);
                *(ushort4*)&ylds[ng][c][0][li] = make_ushort4(hs[0], hs[1], hs[2], hs[3]);
                *(ushort4*)&ylds[ng][c][1][li] = make_ushort4(ls[0], ls[1], ls[2], ls[3]);
            }
        }
    }
    __syncthreads();

    // ---------- phase 2: out1 (+)= Wout_l @ y2 ; !HASNEXT: emit out0 partials ----------
    {
        f32x4 accO[2][3] = {};
        const unsigned short* AoH = Aph + aOffOut;
        const unsigned short* AoL = Apl + aOffOut;
#pragma unroll
        for (int ks = 0; ks < 4; ++ks) {
            short8 yh[3], yl[3];
            int li = (((ks << 2) + (lane >> 4)) << 7) + ((lane & 15) << 3);
#pragma unroll
            for (int c = 0; c < 3; ++c) {
                yh[c] = *(const short8*)&ylds[ng][c][0][li];
                yl[c] = *(const short8*)&ylds[ng][c][1][li];
            }
#pragma unroll
            for (int pi = 0; pi < 2; ++pi) {
                int mf = 2 * mg + pi;
                long aoff = (((long)ks * 8 + mf) * 64 + lane) * 8;
                short8 ah = *(const short8*)(AoH + aoff);
                short8 al = *(const short8*)(AoL + aoff);
#pragma unroll
                for (int c = 0; c < 3; ++c) {
                    accO[pi][c] = __builtin_amdgcn_mfma_f32_16x16x32_bf16(ah, yh[c], accO[pi][c], 0, 0, 0);
                    accO[pi][c] = __builtin_amdgcn_mfma_f32_16x16x32_bf16(ah, yl[c], accO[pi][c], 0, 0, 0);
                    accO[pi][c] = __builtin_amdgcn_mfma_f32_16x16x32_bf16(al, yh[c], accO[pi][c], 0, 0, 0);
                }
            }
        }
#pragma unroll
        for (int pi = 0; pi < 2; ++pi) {
            int obase = 32 * mg + 16 * pi + ((lane >> 4) << 2);
            float Ov[3][4];
#pragma unroll
            for (int r = 0; r < 4; ++r) {
                int o = obase + r;
#pragma unroll
                for (int c = 0; c < 3; ++c) {
                    long off = ((long)(b * 128 + o) * 3 + c) * N + ncol;
                    float v = accO[pi][c][r];
                    if (accum) v += Ofp[off];
                    Ofp[off] = v;
                    Ov[c][r] = v;
                }
            }
            if (!HASNEXT) {
#pragma unroll
                for (int c = 0; c < 3; ++c) {
#pragma unroll
                    for (int r = 0; r < 4; ++r) {
                        float v = Ov[c][r];
                        v += __shfl_xor(v, 1);
                        v += __shfl_xor(v, 2);
                        v += __shfl_xor(v, 4);
                        v += __shfl_xor(v, 8);
                        if ((lane & 15) == 0)
                            part[((long)(b * 3 + c) * 256 + tile * 2 + ng) * 128 + (obase + r)] = v;
                    }
                }
            }
        }
    }

    // ---------- phase 3 (HASNEXT): y1' = LNA(Wl' y2, Ul' y2) -> y1 + yg partials ----------
    if (HASNEXT) {
        f32x4 accP[2][3] = {};
        f32x4 accD[2][3] = {};
        const unsigned short* AnH = Aph + aOffNext;
        const unsigned short* AnL = Apl + aOffNext;
#pragma unroll
        for (int ks = 0; ks < 4; ++ks) {
            short8 bh[3], bl[3];
            int li = (((ks << 2) + (lane >> 4)) << 7) + ((lane & 15) << 3);
#pragma unroll
            for (int c = 0; c < 3; ++c) {
                bh[c] = *(const short8*)&ylds[ng][c][0][li];
                bl[c] = *(const short8*)&ylds[ng][c][1][li];
            }
#pragma unroll
            for (int pi = 0; pi < 2; ++pi) {
                int mf = 2 * mg + pi;
                long aoffP = (((long)ks * 16 + mf) * 64 + lane) * 8;
                short8 ahP = *(const short8*)(AnH + aoffP);
                short8 alP = *(const short8*)(AnL + aoffP);
#pragma unroll
                for (int c = 0; c < 3; ++c) {
                    accP[pi][c] = __builtin_amdgcn_mfma_f32_16x16x32_bf16(ahP, bh[c], accP[pi][c], 0, 0, 0);
                    accP[pi][c] = __builtin_amdgcn_mfma_f32_16x16x32_bf16(ahP, bl[c], accP[pi][c], 0, 0, 0);
                    accP[pi][c] = __builtin_amdgcn_mfma_f32_16x16x32_bf16(alP, bh[c], accP[pi][c], 0, 0, 0);
                }
                long aoffD = (((long)ks * 16 + (8 + mf)) * 64 + lane) * 8;
                short8 ahD = *(const short8*)(AnH + aoffD);
                short8 alD = *(const short8*)(AnL + aoffD);
#pragma unroll
                for (int c = 0; c < 3; ++c) {
                    accD[pi][c] = __builtin_amdgcn_mfma_f32_16x16x32_bf16(ahD, bh[c], accD[pi][c], 0, 0, 0);
                    accD[pi][c] = __builtin_amdgcn_mfma_f32_16x16x32_bf16(ahD, bl[c], accD[pi][c], 0, 0, 0);
                    accD[pi][c] = __builtin_amdgcn_mfma_f32_16x16x32_bf16(alD, bh[c], accD[pi][c], 0, 0, 0);
                }
            }
        }
#pragma unroll
        for (int pi = 0; pi < 2; ++pi) {
            int obase = 32 * mg + 16 * pi + ((lane >> 4) << 2);
            float Pv[3][4];
#pragma unroll
            for (int r = 0; r < 4; ++r) {
                float P[3], D[3];
#pragma unroll
                for (int c = 0; c < 3; ++c) { P[c] = accP[pi][c][r]; D[c] = accD[pi][c][r]; }
                float dot = P[0] * D[0] + P[1] * D[1] + P[2] * D[2];
                float dsq = D[0] * D[0] + D[1] * D[1] + D[2] * D[2];
                if (dot < 0.0f) {
                    float s = dot / (dsq + 1e-6f);
                    P[0] -= s * D[0]; P[1] -= s * D[1]; P[2] -= s * D[2];
                }
                Pv[0][r] = P[0]; Pv[1][r] = P[1]; Pv[2][r] = P[2];
            }
#pragma unroll
            for (int c = 0; c < 3; ++c) {
                unsigned short hs[4], ls[4];
#pragma unroll
                for (int r = 0; r < 4; ++r) {
                    hs[r] = f2bf(Pv[c][r]);
                    ls[r] = f2bf(Pv[c][r] - bf2f(hs[r]));
                }
                long ooff = ((long)(b * 3 + c) * N + ncol) * 128 + obase;
                *(ushort4*)(y1h + ooff) = make_ushort4(hs[0], hs[1], hs[2], hs[3]);
                *(ushort4*)(y1l + ooff) = make_ushort4(ls[0], ls[1], ls[2], ls[3]);
            }
#pragma unroll
            for (int c = 0; c < 3; ++c) {
#pragma unroll
                for (int r = 0; r < 4; ++r) {
                    float v = Pv[c][r];
                    v += __shfl_xor(v, 1);
                    v += __shfl_xor(v, 2);
                    v += __shfl_xor(v, 4);
                    v += __shfl_xor(v, 8);
                    if ((lane & 15) == 0)
                        part[((long)(b * 3 + c) * 256 + tile * 2 + ng) * 128 + (obase + r)] = v;
                }
            }
        }
    }
}

// ---------------- fused yg reduce + bias: 6 blocks (b*3+c), 1024 threads ----------------
__global__ __launch_bounds__(1024) void ygredbias_kernel(const float* __restrict__ part,
                                                         const float* __restrict__ Wg,
                                                         const float* __restrict__ Ug,
                                                         float* __restrict__ biasP,
                                                         float* __restrict__ biasD) {
    __shared__ float red[8][128];
    __shared__ float ygs[128];
    int bc = blockIdx.x;
    int t = threadIdx.x;
    int o = t & 127, g = t >> 7;
    float s = 0.f;
    for (int seg = g * 32; seg < g * 32 + 32; ++seg)
        s += part[((long)bc * 256 + seg) * 128 + o];
    red[g][o] = s;
    __syncthreads();
    if (t < 128) {
        float r = 0.f;
#pragma unroll
        for (int k = 0; k < 8; ++k) r += red[k][t];
        ygs[t] = r * (1.0f / 4096.0f);
    }
    __syncthreads();
    if (t < 256) {
        int oo = t & 127; bool isD = t >= 128;
        const float* row = (isD ? Ug : Wg) + oo * 256 + 128;
        float s2 = 0.f;
        for (int i = 0; i < 128; ++i) s2 = fmaf(row[i], ygs[i], s2);
        int b = bc / 3, c = bc % 3;
        (isD ? biasD : biasP)[((long)(b * 128 + oo)) * 3 + c] = s2;
    }
}

// ---------------- out0 finalize: 6 blocks (b*3+c), 1024 threads ----------------
__global__ __launch_bounds__(1024) void out0red_kernel(const float* __restrict__ part,
                                                       float* __restrict__ out0) {
    __shared__ float red[8][128];
    int bc = blockIdx.x;
    int t = threadIdx.x;
    int o = t & 127, g = t >> 7;
    float s = 0.f;
    for (int seg = g * 32; seg < g * 32 + 32; ++seg)
        s += part[((long)bc * 256 + seg) * 128 + o];
    red[g][o] = s;
    __syncthreads();
    if (t < 128) {
        float r = 0.f;
#pragma unroll
        for (int k = 0; k < 8; ++k) r += red[k][t];
        int b = bc / 3, c = bc % 3;
        out0[((long)(b * 128) + t) * 3 + c] = r * (1.0f / 4096.0f);
    }
}

extern "C" void kernel_launch(void* const* d_in, const int* in_sizes, int n_in,
                              void* d_out, int out_size, void* d_ws, size_t ws_size,
                              hipStream_t stream) {
    const float* x    = (const float*)d_in[0];
    const float* Win  = (const float*)d_in[1];
    const float* Uin  = (const float*)d_in[2];
    const float* Wl   = (const float*)d_in[3];
    const float* Ul   = (const float*)d_in[4];
    const float* Wg   = (const float*)d_in[5];
    const float* Ug   = (const float*)d_in[6];
    const float* Wout = (const float*)d_in[7];

    const int B = 2, N = 4096, H = 128;
    float* out0 = (float*)d_out;                 // (B,128,3) mean
    float* out1 = out0 + (long)B * H * 3;        // (B,128,3,N) fp32

    float* ws = (float*)d_ws;
    long off = 0;
    float4* pts4 = (float4*)ws;                  off += (long)B * N * 4;
    int* idx = (int*)(ws + off);                 off += (long)B * N * 16;
    const long ACT = (long)B * 3 * N * H;        // ushort count
    unsigned short* y1h = (unsigned short*)(ws + off);  off += ACT / 2;
    unsigned short* y1l = (unsigned short*)(ws + off);  off += ACT / 2;
    unsigned short* Aph = (unsigned short*)(ws + off);  off += 327680 / 2;
    unsigned short* Apl = (unsigned short*)(ws + off);  off += 327680 / 2;
    float* part  = ws + off;                     off += 6L * 256 * 128;
    float* biasP = ws + off;                     off += B * H * 3;
    float* biasD = ws + off;                     off += B * H * 3;
    // ~15 MB of workspace

    setup_kernel<<<1280, 256, 0, stream>>>(x, pts4, Wl, Ul, Wg, Ug, Wout, Aph, Apl, N, B);
    knn_kernel<<<B * (N / 16), 1024, 0, stream>>>(pts4, idx, N);

    // edge features + layer-0 input GEMM fused (f0 lives in LDS only)
    edgegemm0_kernel<<<256, 512, 0, stream>>>(pts4, idx, Win, Uin,
                                              Aph, Apl, y1h, y1l, part, N);

    for (int l = 0; l < 4; ++l) {
        ygredbias_kernel<<<6, 1024, 0, stream>>>(part,
            Wg + (long)l * H * 256, Ug + (long)l * H * 256, biasP, biasD);
        long aG = (long)(4 + l) * 32768;
        long aO = 262144 + (long)l * 16384;
        if (l < 3) {
            fused_kernel<true><<<256, 512, 0, stream>>>(
                Aph, Apl, aG, aO, (long)(l + 1) * 32768,
                y1h, y1l, biasP, biasD, out1, part, l > 0 ? 1 : 0);
        } else {
            fused_kernel<false><<<256, 512, 0, stream>>>(
                Aph, Apl, aG, aO, 0L,
                y1h, y1l, biasP, biasD, out1, part, 1);
        }
    }
    out0red_kernel<<<6, 1024, 0, stream>>>(part, out0);
}